// Round 1
// baseline (2169.206 us; speedup 1.0000x reference)
//
#include <hip/hip_runtime.h>
#include <math.h>

#define N_NODES  200000
#define N_EDGES  1600000
#define N_GRAPHS 10000
#define IN_F     74
#define HID      128
#define DEPTH    3

__device__ __forceinline__ float silu_f(float x) {
    return x / (1.0f + __expf(-x));
}

// ---------------- degree / norm ----------------
__global__ void deg_kernel(const int* __restrict__ src, const int* __restrict__ dst,
                           int* __restrict__ deg_out, int* __restrict__ deg_in) {
    int i = blockIdx.x * 256 + threadIdx.x;
    if (i < N_EDGES) {
        atomicAdd(&deg_out[src[i]], 1);
        atomicAdd(&deg_in[dst[i]], 1);
    }
}

__global__ void norm_kernel(const int* __restrict__ deg_out, const int* __restrict__ deg_in,
                            float* __restrict__ norm_src, float* __restrict__ norm_dst) {
    int i = blockIdx.x * 256 + threadIdx.x;
    if (i < N_NODES) {
        norm_src[i] = 1.0f / sqrtf(fmaxf((float)deg_out[i], 1.0f));
        norm_dst[i] = 1.0f / sqrtf(fmaxf((float)deg_in[i], 1.0f));
    }
}

// ---------------- exclusive scan of deg_in -> row_off ----------------
__global__ void scan1_kernel(const int* __restrict__ deg, int* __restrict__ row_off,
                             int* __restrict__ bsums) {
    __shared__ int a[256], b[256];
    int t = threadIdx.x;
    int i = blockIdx.x * 256 + t;
    a[t] = (i < N_NODES) ? deg[i] : 0;
    __syncthreads();
    int* s = a; int* d = b;
    #pragma unroll
    for (int off = 1; off < 256; off <<= 1) {
        int val = s[t];
        if (t >= off) val += s[t - off];
        d[t] = val;
        __syncthreads();
        int* tmp = s; s = d; d = tmp;
    }
    if (i < N_NODES) row_off[i + 1] = s[t];
    if (t == 255) bsums[blockIdx.x] = s[255];
    if (i == 0) row_off[0] = 0;
}

__global__ void scan2_kernel(int* __restrict__ bsums, int nb) {
    __shared__ int a[1024], b[1024];
    int t = threadIdx.x;
    a[t] = (t < nb) ? bsums[t] : 0;
    __syncthreads();
    int* s = a; int* d = b;
    for (int off = 1; off < 1024; off <<= 1) {
        int val = s[t];
        if (t >= off) val += s[t - off];
        d[t] = val;
        __syncthreads();
        int* tmp = s; s = d; d = tmp;
    }
    if (t < nb) bsums[t] = s[t];
}

__global__ void scan3_kernel(int* __restrict__ row_off, const int* __restrict__ bsums) {
    int i = blockIdx.x * 256 + threadIdx.x;
    if (i < N_NODES && blockIdx.x > 0)
        row_off[i + 1] += bsums[blockIdx.x - 1];
}

__global__ void fill_kernel(const int* __restrict__ src, const int* __restrict__ dst,
                            const int* __restrict__ row_off, int* __restrict__ cursor,
                            int* __restrict__ esrc) {
    int e = blockIdx.x * 256 + threadIdx.x;
    if (e < N_EDGES) {
        int d = dst[e];
        int pos = atomicAdd(&cursor[d], 1);
        esrc[row_off[d] + pos] = src[e];
    }
}

// ---------------- pull-based SpMM: agg[d] = norm_dst[d] * sum_{s in N(d)} norm_src[s]*h[s] ----------------
__global__ void spmm_kernel(const float* __restrict__ h, const int* __restrict__ esrc,
                            const int* __restrict__ row_off,
                            const float* __restrict__ norm_src, const float* __restrict__ norm_dst,
                            float* __restrict__ agg) {
    int t = threadIdx.x;
    int node = blockIdx.x * 8 + (t >> 5);
    if (node >= N_NODES) return;
    int lane = t & 31;
    int beg = row_off[node], end = row_off[node + 1];
    float4 acc = {0.f, 0.f, 0.f, 0.f};
    for (int j = beg; j < end; ++j) {
        int s = esrc[j];
        float ns = norm_src[s];
        float4 v = ((const float4*)(h + (size_t)s * HID))[lane];
        acc.x += v.x * ns; acc.y += v.y * ns; acc.z += v.z * ns; acc.w += v.w * ns;
    }
    float nd = norm_dst[node];
    acc.x *= nd; acc.y *= nd; acc.z *= nd; acc.w *= nd;
    ((float4*)(agg + (size_t)node * HID))[lane] = acc;
}

// ---------------- fp32 GEMM: out[nrows x 128] = act(in[nrows x K] @ W[K x 128] + bias) ----------------
template<int K, bool DO_SILU>
__launch_bounds__(256)
__global__ void gemm_kernel(const float* __restrict__ in, const float* __restrict__ W,
                            const float* __restrict__ bias, float* __restrict__ out, int nrows) {
    __shared__ float wl[64 * HID];   // 32 KB chunk of W
    __shared__ float xl[32 * K];     // 32-row input tile
    int t = threadIdx.x;
    int row0 = blockIdx.x * 32;

    for (int i = t; i < 32 * K; i += 256) {
        int r = i / K, k = i - r * K;
        int gr = row0 + r;
        xl[i] = (gr < nrows) ? in[(size_t)gr * K + k] : 0.0f;
    }

    int col = t & (HID - 1);
    int rg  = t >> 7;   // 0 or 1: which 16-row group
    float acc[16];
    #pragma unroll
    for (int rr = 0; rr < 16; ++rr) acc[rr] = 0.0f;

    for (int c = 0; c < K; c += 64) {
        int kc = (K - c < 64) ? (K - c) : 64;
        __syncthreads();   // wl safe to overwrite; also covers initial xl fill
        for (int i = t; i < kc * HID; i += 256) wl[i] = W[(size_t)c * HID + i];
        __syncthreads();
        for (int kk = 0; kk < kc; ++kk) {
            float w = wl[kk * HID + col];
            int k = c + kk;
            #pragma unroll
            for (int rr = 0; rr < 16; ++rr)
                acc[rr] += xl[(rg * 16 + rr) * K + k] * w;
        }
    }

    float b = bias[col];
    #pragma unroll
    for (int rr = 0; rr < 16; ++rr) {
        int r = row0 + rg * 16 + rr;
        if (r < nrows) {
            float v = acc[rr] + b;
            if (DO_SILU) v = silu_f(v);
            out[(size_t)r * HID + col] = v;
        }
    }
}

// ---------------- pooling: pooled[g] += h[n] ----------------
__global__ void pool_kernel(const float* __restrict__ h, const int* __restrict__ gid,
                            float* __restrict__ pooled) {
    int idx = blockIdx.x * 256 + threadIdx.x;
    int n = idx >> 5, lane = idx & 31;
    if (n >= N_NODES) return;
    int g = gid[n];
    float4 v = ((const float4*)(h + (size_t)n * HID))[lane];
    float* p = pooled + (size_t)g * HID + lane * 4;
    atomicAdd(p + 0, v.x);
    atomicAdd(p + 1, v.y);
    atomicAdd(p + 2, v.z);
    atomicAdd(p + 3, v.w);
}

extern "C" void kernel_launch(void* const* d_in, const int* in_sizes, int n_in,
                              void* d_out, int out_size, void* d_ws, size_t ws_size,
                              hipStream_t stream) {
    const float* x     = (const float*)d_in[0];
    const int*   src   = (const int*)  d_in[1];
    const int*   dst   = (const int*)  d_in[2];
    const int*   gid   = (const int*)  d_in[3];
    const float* w_in  = (const float*)d_in[4];
    const float* b_in  = (const float*)d_in[5];
    const float* gw    = (const float*)d_in[6];
    const float* gb    = (const float*)d_in[7];
    const float* w_out = (const float*)d_in[8];
    const float* b_out = (const float*)d_in[9];
    const float* w_ff  = (const float*)d_in[10];
    const float* b_ff  = (const float*)d_in[11];
    float* out = (float*)d_out;

    // workspace layout
    char* w = (char*)d_ws;
    size_t off = 0;
    auto alloc = [&](size_t bytes) { void* p = w + off; off += (bytes + 255) & ~(size_t)255; return p; };
    float* h0       = (float*)alloc((size_t)N_NODES * HID * 4);
    float* h1       = (float*)alloc((size_t)N_NODES * HID * 4);
    float* norm_src = (float*)alloc((size_t)N_NODES * 4);
    float* norm_dst = (float*)alloc((size_t)N_NODES * 4);
    int*   deg_out  = (int*)  alloc((size_t)N_NODES * 4);
    int*   deg_in   = (int*)  alloc((size_t)N_NODES * 4);
    int*   cursor   = (int*)  alloc((size_t)N_NODES * 4);
    int*   row_off  = (int*)  alloc((size_t)(N_NODES + 1) * 4);
    int*   esrc     = (int*)  alloc((size_t)N_EDGES * 4);
    int*   bsums    = (int*)  alloc(1024 * 4);
    float* pooled   = (float*)alloc((size_t)N_GRAPHS * HID * 4);

    const int NB_NODES = (N_NODES + 255) / 256;   // 782
    const int NB_EDGES = (N_EDGES + 255) / 256;   // 6250

    // degrees + norms + CSR (once; shared by all 3 convs)
    hipMemsetAsync(deg_out, 0, (size_t)N_NODES * 4, stream);
    hipMemsetAsync(deg_in,  0, (size_t)N_NODES * 4, stream);
    hipMemsetAsync(cursor,  0, (size_t)N_NODES * 4, stream);
    deg_kernel<<<NB_EDGES, 256, 0, stream>>>(src, dst, deg_out, deg_in);
    norm_kernel<<<NB_NODES, 256, 0, stream>>>(deg_out, deg_in, norm_src, norm_dst);
    scan1_kernel<<<NB_NODES, 256, 0, stream>>>(deg_in, row_off, bsums);
    scan2_kernel<<<1, 1024, 0, stream>>>(bsums, NB_NODES);
    scan3_kernel<<<NB_NODES, 256, 0, stream>>>(row_off, bsums);
    fill_kernel<<<NB_EDGES, 256, 0, stream>>>(src, dst, row_off, cursor, esrc);

    // h0 = silu(x @ w_in + b_in)
    gemm_kernel<IN_F, true><<<(N_NODES + 31) / 32, 256, 0, stream>>>(x, w_in, b_in, h0, N_NODES);

    // 3 graph convs
    for (int i = 0; i < DEPTH; ++i) {
        spmm_kernel<<<(N_NODES + 7) / 8, 256, 0, stream>>>(h0, esrc, row_off, norm_src, norm_dst, h1);
        gemm_kernel<HID, true><<<(N_NODES + 31) / 32, 256, 0, stream>>>(
            h1, gw + (size_t)i * HID * HID, gb + (size_t)i * HID, h0, N_NODES);
    }

    // h1 = silu(h0 @ w_out + b_out)
    gemm_kernel<HID, true><<<(N_NODES + 31) / 32, 256, 0, stream>>>(h0, w_out, b_out, h1, N_NODES);

    // pooled = segment_sum(h1, gid)
    hipMemsetAsync(pooled, 0, (size_t)N_GRAPHS * HID * 4, stream);
    pool_kernel<<<(N_NODES * 32 + 255) / 256, 256, 0, stream>>>(h1, gid, pooled);

    // out = pooled @ w_ff + b_ff
    gemm_kernel<HID, false><<<(N_GRAPHS + 31) / 32, 256, 0, stream>>>(pooled, w_ff, b_ff, out, N_GRAPHS);
}

// Round 2
// 1211.030 us; speedup vs baseline: 1.7912x; 1.7912x over previous
//
#include <hip/hip_runtime.h>
#include <math.h>

#define N_NODES  200000
#define N_EDGES  1600000
#define N_GRAPHS 10000
#define IN_F     74
#define HID      128
#define DEPTH    3

typedef __attribute__((ext_vector_type(8))) short short8;
typedef __attribute__((ext_vector_type(4))) float floatx4;
typedef __attribute__((ext_vector_type(4))) unsigned short ushort4v;

__device__ __forceinline__ float silu_f(float x) {
    return x / (1.0f + __expf(-x));
}

__device__ __forceinline__ unsigned short f2bf(float f) {
    union { float f; unsigned int u; } v; v.f = f;
    unsigned int r = (v.u + 0x7fff + ((v.u >> 16) & 1)) >> 16;   // RNE
    return (unsigned short)r;
}

// ---------------- degree / norm ----------------
__global__ void deg_kernel(const int* __restrict__ src, const int* __restrict__ dst,
                           int* __restrict__ deg_out, int* __restrict__ deg_in) {
    int i = blockIdx.x * 256 + threadIdx.x;
    if (i < N_EDGES) {
        atomicAdd(&deg_out[src[i]], 1);
        atomicAdd(&deg_in[dst[i]], 1);
    }
}

__global__ void norm_kernel(const int* __restrict__ deg_out, const int* __restrict__ deg_in,
                            float* __restrict__ norm_src, float* __restrict__ norm_dst) {
    int i = blockIdx.x * 256 + threadIdx.x;
    if (i < N_NODES) {
        norm_src[i] = 1.0f / sqrtf(fmaxf((float)deg_out[i], 1.0f));
        norm_dst[i] = 1.0f / sqrtf(fmaxf((float)deg_in[i], 1.0f));
    }
}

// ---------------- exclusive scan of deg_in -> row_off ----------------
__global__ void scan1_kernel(const int* __restrict__ deg, int* __restrict__ row_off,
                             int* __restrict__ bsums) {
    __shared__ int a[256], b[256];
    int t = threadIdx.x;
    int i = blockIdx.x * 256 + t;
    a[t] = (i < N_NODES) ? deg[i] : 0;
    __syncthreads();
    int* s = a; int* d = b;
    #pragma unroll
    for (int off = 1; off < 256; off <<= 1) {
        int val = s[t];
        if (t >= off) val += s[t - off];
        d[t] = val;
        __syncthreads();
        int* tmp = s; s = d; d = tmp;
    }
    if (i < N_NODES) row_off[i + 1] = s[t];
    if (t == 255) bsums[blockIdx.x] = s[255];
    if (i == 0) row_off[0] = 0;
}

__global__ void scan2_kernel(int* __restrict__ bsums, int nb) {
    __shared__ int a[1024], b[1024];
    int t = threadIdx.x;
    a[t] = (t < nb) ? bsums[t] : 0;
    __syncthreads();
    int* s = a; int* d = b;
    for (int off = 1; off < 1024; off <<= 1) {
        int val = s[t];
        if (t >= off) val += s[t - off];
        d[t] = val;
        __syncthreads();
        int* tmp = s; s = d; d = tmp;
    }
    if (t < nb) bsums[t] = s[t];
}

__global__ void scan3_kernel(int* __restrict__ row_off, const int* __restrict__ bsums) {
    int i = blockIdx.x * 256 + threadIdx.x;
    if (i < N_NODES && blockIdx.x > 0)
        row_off[i + 1] += bsums[blockIdx.x - 1];
}

__global__ void fill_kernel(const int* __restrict__ src, const int* __restrict__ dst,
                            const int* __restrict__ row_off, int* __restrict__ cursor,
                            int* __restrict__ esrc) {
    int e = blockIdx.x * 256 + threadIdx.x;
    if (e < N_EDGES) {
        int d = dst[e];
        int pos = atomicAdd(&cursor[d], 1);
        esrc[row_off[d] + pos] = src[e];
    }
}

// ---------------- pull-based SpMM ----------------
__global__ void spmm_kernel(const float* __restrict__ h, const int* __restrict__ esrc,
                            const int* __restrict__ row_off,
                            const float* __restrict__ norm_src, const float* __restrict__ norm_dst,
                            float* __restrict__ agg) {
    int t = threadIdx.x;
    int node = blockIdx.x * 8 + (t >> 5);
    if (node >= N_NODES) return;
    int lane = t & 31;
    int beg = row_off[node], end = row_off[node + 1];
    float4 acc = {0.f, 0.f, 0.f, 0.f};
    for (int j = beg; j < end; ++j) {
        int s = esrc[j];
        float ns = norm_src[s];
        float4 v = ((const float4*)(h + (size_t)s * HID))[lane];
        acc.x += v.x * ns; acc.y += v.y * ns; acc.z += v.z * ns; acc.w += v.w * ns;
    }
    float nd = norm_dst[node];
    acc.x *= nd; acc.y *= nd; acc.z *= nd; acc.w *= nd;
    ((float4*)(agg + (size_t)node * HID))[lane] = acc;
}

// ---------------- weight prep: fp32 [K][128] -> bf16 WT [128][KP] (transposed, padded) ----------------
__global__ void wprep_kernel(const float* __restrict__ w_in, const float* __restrict__ gw,
                             const float* __restrict__ w_out,
                             unsigned short* __restrict__ wtin,   // [128][96]
                             unsigned short* __restrict__ wtg,    // [3][128][128]
                             unsigned short* __restrict__ wtout)  // [128][128]
{
    int i = blockIdx.x * 256 + threadIdx.x;
    if (i < 128 * 96) {
        int n = i / 96, k = i - n * 96;
        wtin[i] = (k < IN_F) ? f2bf(w_in[k * 128 + n]) : (unsigned short)0;
    } else if (i < 128 * 96 + 3 * 128 * 128) {
        int j = i - 128 * 96;
        int layer = j / 16384, r = j - layer * 16384;
        int n = r >> 7, k = r & 127;
        wtg[j] = f2bf(gw[((size_t)layer * 128 + k) * 128 + n]);
    } else if (i < 128 * 96 + 3 * 128 * 128 + 128 * 128) {
        int j = i - (128 * 96 + 3 * 128 * 128);
        int n = j >> 7, k = j & 127;
        wtout[j] = f2bf(w_out[k * 128 + n]);
    }
}

// ---------------- bf16 MFMA GEMM: out[nrows x 128] = act(in[nrows x K_IN] @ W + bias) ----------------
// Block: 256 threads = 4 waves; block tile 64 rows x 128 cols; wave tile 32 rows x 64 cols.
template<int K_IN, int KP, bool DO_SILU>
__launch_bounds__(256)
__global__ void mfma_gemm(const float* __restrict__ in, const unsigned short* __restrict__ WT,
                          const float* __restrict__ bias, float* __restrict__ out, int nrows) {
    constexpr int KSTEPS = KP / 32;
    __shared__ unsigned short lds_a[64 * 136];   // +8 pad: 2-way bank alias only (free)
    const int t = threadIdx.x;
    const int rowbase = blockIdx.x * 64;

    // ---- stage A tile fp32 -> bf16 into LDS ----
    if constexpr (K_IN == 128) {
        #pragma unroll
        for (int j = 0; j < 8; ++j) {
            int e = j * 256 + t;          // float4 slot id
            int r = e >> 5;               // /32 slots per row
            int k = (e & 31) * 4;
            int row = rowbase + r;
            float4 v = {0.f, 0.f, 0.f, 0.f};
            if (row < nrows) v = *(const float4*)(in + (size_t)row * 128 + k);
            ushort4v u;
            u.x = f2bf(v.x); u.y = f2bf(v.y); u.z = f2bf(v.z); u.w = f2bf(v.w);
            *(ushort4v*)&lds_a[r * 136 + k] = u;
        }
    } else {
        for (int i = t; i < 64 * KP; i += 256) {
            int r = i / KP, k = i - r * KP;
            int row = rowbase + r;
            float v = (k < K_IN && row < nrows) ? in[(size_t)row * K_IN + k] : 0.0f;
            lds_a[r * 136 + k] = f2bf(v);
        }
    }

    const int lane = t & 63;
    const int w  = t >> 6;
    const int wr = w & 1;        // row half
    const int wc = w >> 1;       // col half
    const int l15 = lane & 15, quad = lane >> 4;

    // ---- B fragments from global (WT is <=32KB, L1/L2-hot) ----
    short8 bfrag[KSTEPS][4];
    #pragma unroll
    for (int ks = 0; ks < KSTEPS; ++ks)
        #pragma unroll
        for (int tn = 0; tn < 4; ++tn) {
            int n = wc * 64 + tn * 16 + l15;
            bfrag[ks][tn] = *(const short8*)(WT + (size_t)n * KP + ks * 32 + quad * 8);
        }

    floatx4 acc[4][2];
    #pragma unroll
    for (int tn = 0; tn < 4; ++tn)
        #pragma unroll
        for (int rt = 0; rt < 2; ++rt)
            acc[tn][rt] = (floatx4){0.f, 0.f, 0.f, 0.f};

    __syncthreads();

    #pragma unroll
    for (int ks = 0; ks < KSTEPS; ++ks) {
        short8 af[2];
        #pragma unroll
        for (int rt = 0; rt < 2; ++rt) {
            int m = wr * 32 + rt * 16 + l15;
            af[rt] = *(const short8*)&lds_a[m * 136 + ks * 32 + quad * 8];
        }
        #pragma unroll
        for (int tn = 0; tn < 4; ++tn)
            #pragma unroll
            for (int rt = 0; rt < 2; ++rt)
                acc[tn][rt] = __builtin_amdgcn_mfma_f32_16x16x32_bf16(
                    af[rt], bfrag[ks][tn], acc[tn][rt], 0, 0, 0);
    }

    // ---- epilogue: bias + SiLU + store (C/D: col=lane&15, row=quad*4+reg) ----
    #pragma unroll
    for (int tn = 0; tn < 4; ++tn) {
        int col = wc * 64 + tn * 16 + l15;
        float b = bias[col];
        #pragma unroll
        for (int rt = 0; rt < 2; ++rt) {
            #pragma unroll
            for (int r = 0; r < 4; ++r) {
                int row = rowbase + wr * 32 + rt * 16 + quad * 4 + r;
                if (row < nrows) {
                    float v = acc[tn][rt][r] + b;
                    if (DO_SILU) v = silu_f(v);
                    out[(size_t)row * 128 + col] = v;
                }
            }
        }
    }
}

// ---------------- fp32 GEMM (kept for the small final matmul) ----------------
template<int K, bool DO_SILU>
__launch_bounds__(256)
__global__ void gemm_kernel(const float* __restrict__ in, const float* __restrict__ W,
                            const float* __restrict__ bias, float* __restrict__ out, int nrows) {
    __shared__ float wl[64 * HID];
    __shared__ float xl[32 * K];
    int t = threadIdx.x;
    int row0 = blockIdx.x * 32;

    for (int i = t; i < 32 * K; i += 256) {
        int r = i / K, k = i - r * K;
        int gr = row0 + r;
        xl[i] = (gr < nrows) ? in[(size_t)gr * K + k] : 0.0f;
    }

    int col = t & (HID - 1);
    int rg  = t >> 7;
    float acc[16];
    #pragma unroll
    for (int rr = 0; rr < 16; ++rr) acc[rr] = 0.0f;

    for (int c = 0; c < K; c += 64) {
        int kc = (K - c < 64) ? (K - c) : 64;
        __syncthreads();
        for (int i = t; i < kc * HID; i += 256) wl[i] = W[(size_t)c * HID + i];
        __syncthreads();
        for (int kk = 0; kk < kc; ++kk) {
            float w = wl[kk * HID + col];
            int k = c + kk;
            #pragma unroll
            for (int rr = 0; rr < 16; ++rr)
                acc[rr] += xl[(rg * 16 + rr) * K + k] * w;
        }
    }

    float b = bias[col];
    #pragma unroll
    for (int rr = 0; rr < 16; ++rr) {
        int r = row0 + rg * 16 + rr;
        if (r < nrows) {
            float v = acc[rr] + b;
            if (DO_SILU) v = silu_f(v);
            out[(size_t)r * HID + col] = v;
        }
    }
}

// ---------------- pooling: sorted graph_ids -> segmented sum, no atomics ----------------
__device__ __forceinline__ int lower_bound_gid(const int* __restrict__ gid, int val) {
    int lo = 0, hi = N_NODES;
    while (lo < hi) {
        int mid = (lo + hi) >> 1;
        if (gid[mid] < val) lo = mid + 1; else hi = mid;
    }
    return lo;
}

__global__ void pool_kernel(const float* __restrict__ h, const int* __restrict__ gid,
                            float* __restrict__ pooled) {
    int g = blockIdx.x;
    int t = threadIdx.x;   // 128 threads, one per column
    int beg = lower_bound_gid(gid, g);
    int end = lower_bound_gid(gid, g + 1);
    float s = 0.0f;
    for (int n = beg; n < end; ++n)
        s += h[(size_t)n * HID + t];
    pooled[(size_t)g * HID + t] = s;
}

extern "C" void kernel_launch(void* const* d_in, const int* in_sizes, int n_in,
                              void* d_out, int out_size, void* d_ws, size_t ws_size,
                              hipStream_t stream) {
    const float* x     = (const float*)d_in[0];
    const int*   src   = (const int*)  d_in[1];
    const int*   dst   = (const int*)  d_in[2];
    const int*   gid   = (const int*)  d_in[3];
    const float* w_in  = (const float*)d_in[4];
    const float* b_in  = (const float*)d_in[5];
    const float* gw    = (const float*)d_in[6];
    const float* gb    = (const float*)d_in[7];
    const float* w_out = (const float*)d_in[8];
    const float* b_out = (const float*)d_in[9];
    const float* w_ff  = (const float*)d_in[10];
    const float* b_ff  = (const float*)d_in[11];
    float* out = (float*)d_out;

    char* w = (char*)d_ws;
    size_t off = 0;
    auto alloc = [&](size_t bytes) { void* p = w + off; off += (bytes + 255) & ~(size_t)255; return p; };
    float* h0       = (float*)alloc((size_t)N_NODES * HID * 4);
    float* h1       = (float*)alloc((size_t)N_NODES * HID * 4);
    float* norm_src = (float*)alloc((size_t)N_NODES * 4);
    float* norm_dst = (float*)alloc((size_t)N_NODES * 4);
    int*   deg_out  = (int*)  alloc((size_t)N_NODES * 4);
    int*   deg_in   = (int*)  alloc((size_t)N_NODES * 4);
    int*   cursor   = (int*)  alloc((size_t)N_NODES * 4);
    int*   row_off  = (int*)  alloc((size_t)(N_NODES + 1) * 4);
    int*   esrc     = (int*)  alloc((size_t)N_EDGES * 4);
    int*   bsums    = (int*)  alloc(1024 * 4);
    float* pooled   = (float*)alloc((size_t)N_GRAPHS * HID * 4);
    unsigned short* wtin  = (unsigned short*)alloc(128 * 96 * 2);
    unsigned short* wtg   = (unsigned short*)alloc(3 * 128 * 128 * 2);
    unsigned short* wtout = (unsigned short*)alloc(128 * 128 * 2);

    const int NB_NODES = (N_NODES + 255) / 256;   // 782
    const int NB_EDGES = (N_EDGES + 255) / 256;   // 6250

    // degrees + norms + CSR (once; shared by all 3 convs) + weight prep
    hipMemsetAsync(deg_out, 0, (size_t)N_NODES * 4, stream);
    hipMemsetAsync(deg_in,  0, (size_t)N_NODES * 4, stream);
    hipMemsetAsync(cursor,  0, (size_t)N_NODES * 4, stream);
    deg_kernel<<<NB_EDGES, 256, 0, stream>>>(src, dst, deg_out, deg_in);
    norm_kernel<<<NB_NODES, 256, 0, stream>>>(deg_out, deg_in, norm_src, norm_dst);
    scan1_kernel<<<NB_NODES, 256, 0, stream>>>(deg_in, row_off, bsums);
    scan2_kernel<<<1, 1024, 0, stream>>>(bsums, NB_NODES);
    scan3_kernel<<<NB_NODES, 256, 0, stream>>>(row_off, bsums);
    fill_kernel<<<NB_EDGES, 256, 0, stream>>>(src, dst, row_off, cursor, esrc);
    wprep_kernel<<<(128 * 96 + 4 * 128 * 128 + 255) / 256, 256, 0, stream>>>(
        w_in, gw, w_out, wtin, wtg, wtout);

    const int NB_M = (N_NODES + 63) / 64;   // 3125

    // h0 = silu(x @ w_in + b_in)   [bf16 MFMA, K padded 74->96]
    mfma_gemm<IN_F, 96, true><<<NB_M, 256, 0, stream>>>(x, wtin, b_in, h0, N_NODES);

    // 3 graph convs
    for (int i = 0; i < DEPTH; ++i) {
        spmm_kernel<<<(N_NODES + 7) / 8, 256, 0, stream>>>(h0, esrc, row_off, norm_src, norm_dst, h1);
        mfma_gemm<HID, 128, true><<<NB_M, 256, 0, stream>>>(
            h1, wtg + (size_t)i * HID * HID, gb + (size_t)i * HID, h0, N_NODES);
    }

    // h1 = silu(h0 @ w_out + b_out)
    mfma_gemm<HID, 128, true><<<NB_M, 256, 0, stream>>>(h0, wtout, b_out, h1, N_NODES);

    // pooled = segment_sum(h1, gid)  -- gid sorted, segmented, no atomics
    pool_kernel<<<N_GRAPHS, HID, 0, stream>>>(h1, gid, pooled);

    // out = pooled @ w_ff + b_ff   (small, keep fp32 for accuracy)
    gemm_kernel<HID, false><<<(N_GRAPHS + 31) / 32, 256, 0, stream>>>(pooled, w_ff, b_ff, out, N_GRAPHS);
}

// Round 3
// 931.715 us; speedup vs baseline: 2.3282x; 1.2998x over previous
//
#include <hip/hip_runtime.h>
#include <math.h>

#define N_NODES  200000
#define N_EDGES  1600000
#define N_GRAPHS 10000
#define IN_F     74
#define HID      128
#define DEPTH    3

typedef __attribute__((ext_vector_type(8))) short short8;
typedef __attribute__((ext_vector_type(8))) unsigned short ushort8v;
typedef __attribute__((ext_vector_type(4))) float floatx4;
typedef __attribute__((ext_vector_type(4))) unsigned short ushort4v;

__device__ __forceinline__ float silu_f(float x) {
    return x / (1.0f + __expf(-x));
}

__device__ __forceinline__ unsigned short f2bf(float f) {
    union { float f; unsigned int u; } v; v.f = f;
    unsigned int r = (v.u + 0x7fff + ((v.u >> 16) & 1)) >> 16;   // RNE
    return (unsigned short)r;
}

__device__ __forceinline__ float bf2f(unsigned short u) {
    union { unsigned int u; float f; } v; v.u = ((unsigned int)u) << 16;
    return v.f;
}

// ---------------- degree / norm ----------------
__global__ void deg_kernel(const int* __restrict__ src, const int* __restrict__ dst,
                           int* __restrict__ deg_out, int* __restrict__ deg_in) {
    int i = blockIdx.x * 256 + threadIdx.x;
    if (i < N_EDGES) {
        atomicAdd(&deg_out[src[i]], 1);
        atomicAdd(&deg_in[dst[i]], 1);
    }
}

__global__ void norm_kernel(const int* __restrict__ deg_out, const int* __restrict__ deg_in,
                            float* __restrict__ norm_src, float* __restrict__ norm_dst) {
    int i = blockIdx.x * 256 + threadIdx.x;
    if (i < N_NODES) {
        norm_src[i] = 1.0f / sqrtf(fmaxf((float)deg_out[i], 1.0f));
        norm_dst[i] = 1.0f / sqrtf(fmaxf((float)deg_in[i], 1.0f));
    }
}

// ---------------- exclusive scan of deg_in -> row_off ----------------
__global__ void scan1_kernel(const int* __restrict__ deg, int* __restrict__ row_off,
                             int* __restrict__ bsums) {
    __shared__ int a[256], b[256];
    int t = threadIdx.x;
    int i = blockIdx.x * 256 + t;
    a[t] = (i < N_NODES) ? deg[i] : 0;
    __syncthreads();
    int* s = a; int* d = b;
    #pragma unroll
    for (int off = 1; off < 256; off <<= 1) {
        int val = s[t];
        if (t >= off) val += s[t - off];
        d[t] = val;
        __syncthreads();
        int* tmp = s; s = d; d = tmp;
    }
    if (i < N_NODES) row_off[i + 1] = s[t];
    if (t == 255) bsums[blockIdx.x] = s[255];
    if (i == 0) row_off[0] = 0;
}

__global__ void scan2_kernel(int* __restrict__ bsums, int nb) {
    __shared__ int a[1024], b[1024];
    int t = threadIdx.x;
    a[t] = (t < nb) ? bsums[t] : 0;
    __syncthreads();
    int* s = a; int* d = b;
    for (int off = 1; off < 1024; off <<= 1) {
        int val = s[t];
        if (t >= off) val += s[t - off];
        d[t] = val;
        __syncthreads();
        int* tmp = s; s = d; d = tmp;
    }
    if (t < nb) bsums[t] = s[t];
}

__global__ void scan3_kernel(int* __restrict__ row_off, const int* __restrict__ bsums) {
    int i = blockIdx.x * 256 + threadIdx.x;
    if (i < N_NODES && blockIdx.x > 0)
        row_off[i + 1] += bsums[blockIdx.x - 1];
}

__global__ void fill_kernel(const int* __restrict__ src, const int* __restrict__ dst,
                            const int* __restrict__ row_off, int* __restrict__ cursor,
                            int* __restrict__ esrc) {
    int e = blockIdx.x * 256 + threadIdx.x;
    if (e < N_EDGES) {
        int d = dst[e];
        int pos = atomicAdd(&cursor[d], 1);
        esrc[row_off[d] + pos] = src[e];
    }
}

// ---------------- pull-based SpMM, bf16 in/out ----------------
// h is pre-scaled by norm_src (folded into producer GEMM epilogue).
// agg[d] = norm_dst[d] * sum_{s in N(d)} h[s]     16 lanes per node, 16 B per lane.
__global__ void spmm_bf16(const unsigned short* __restrict__ h, const int* __restrict__ esrc,
                          const int* __restrict__ row_off,
                          const float* __restrict__ norm_dst,
                          unsigned short* __restrict__ agg) {
    int t = threadIdx.x;
    int node = blockIdx.x * 16 + (t >> 4);
    if (node >= N_NODES) return;
    int lane = t & 15;
    int beg = row_off[node], end = row_off[node + 1];
    float acc[8];
    #pragma unroll
    for (int q = 0; q < 8; ++q) acc[q] = 0.0f;

    int j = beg;
    for (; j + 1 < end; j += 2) {
        int s0 = esrc[j], s1 = esrc[j + 1];
        ushort8v v0 = *(const ushort8v*)(h + (size_t)s0 * HID + lane * 8);
        ushort8v v1 = *(const ushort8v*)(h + (size_t)s1 * HID + lane * 8);
        #pragma unroll
        for (int q = 0; q < 8; ++q)
            acc[q] += bf2f(v0[q]) + bf2f(v1[q]);
    }
    if (j < end) {
        int s0 = esrc[j];
        ushort8v v0 = *(const ushort8v*)(h + (size_t)s0 * HID + lane * 8);
        #pragma unroll
        for (int q = 0; q < 8; ++q)
            acc[q] += bf2f(v0[q]);
    }

    float nd = norm_dst[node];
    ushort8v o;
    #pragma unroll
    for (int q = 0; q < 8; ++q) o[q] = f2bf(acc[q] * nd);
    *(ushort8v*)(agg + (size_t)node * HID + lane * 8) = o;
}

// ---------------- weight prep: fp32 [K][128] -> bf16 WT [128][KP] (transposed, padded) ----------------
__global__ void wprep_kernel(const float* __restrict__ w_in, const float* __restrict__ gw,
                             const float* __restrict__ w_out,
                             unsigned short* __restrict__ wtin,   // [128][96]
                             unsigned short* __restrict__ wtg,    // [3][128][128]
                             unsigned short* __restrict__ wtout)  // [128][128]
{
    int i = blockIdx.x * 256 + threadIdx.x;
    if (i < 128 * 96) {
        int n = i / 96, k = i - n * 96;
        wtin[i] = (k < IN_F) ? f2bf(w_in[k * 128 + n]) : (unsigned short)0;
    } else if (i < 128 * 96 + 3 * 128 * 128) {
        int j = i - 128 * 96;
        int layer = j / 16384, r = j - layer * 16384;
        int n = r >> 7, k = r & 127;
        wtg[j] = f2bf(gw[((size_t)layer * 128 + k) * 128 + n]);
    } else if (i < 128 * 96 + 3 * 128 * 128 + 128 * 128) {
        int j = i - (128 * 96 + 3 * 128 * 128);
        int n = j >> 7, k = j & 127;
        wtout[j] = f2bf(w_out[k * 128 + n]);
    }
}

// ---------------- bf16 MFMA GEMM ----------------
// Block: 256 threads = 4 waves; block tile 64 rows x 128 cols; wave tile 32 rows x 64 cols.
// A_BF16: input already bf16 [nrows][K_IN]; else fp32 (converted at stage).
// OUT_BF16: write bf16; SCALE_NORM: multiply by norm_src[row] in epilogue (for SpMM consumers).
template<int K_IN, int KP, bool DO_SILU, bool A_BF16, bool OUT_BF16, bool SCALE_NORM>
__launch_bounds__(256)
__global__ void mfma_gemm(const void* __restrict__ in_, const unsigned short* __restrict__ WT,
                          const float* __restrict__ bias, const float* __restrict__ norm_src,
                          void* __restrict__ out_, int nrows) {
    constexpr int KSTEPS = KP / 32;
    __shared__ unsigned short lds_a[64 * 136];   // +8 pad: 2-way bank alias only (free)
    const int t = threadIdx.x;
    const int rowbase = blockIdx.x * 64;

    // ---- stage A tile into LDS (bf16) ----
    if constexpr (A_BF16) {
        const unsigned short* in = (const unsigned short*)in_;
        #pragma unroll
        for (int j = 0; j < 4; ++j) {
            int e = j * 256 + t;          // ushort8 slot id, 16 per row
            int r = e >> 4;
            int c = (e & 15) * 8;
            int row = rowbase + r;
            ushort8v u = {0,0,0,0,0,0,0,0};
            if (row < nrows) u = *(const ushort8v*)(in + (size_t)row * K_IN + c);
            *(ushort8v*)&lds_a[r * 136 + c] = u;
        }
    } else {
        const float* in = (const float*)in_;
        for (int i = t; i < 64 * KP; i += 256) {
            int r = i / KP, k = i - r * KP;
            int row = rowbase + r;
            float v = (k < K_IN && row < nrows) ? in[(size_t)row * K_IN + k] : 0.0f;
            lds_a[r * 136 + k] = f2bf(v);
        }
    }

    const int lane = t & 63;
    const int w  = t >> 6;
    const int wr = w & 1;        // row half
    const int wc = w >> 1;       // col half
    const int l15 = lane & 15, quad = lane >> 4;

    // ---- B fragments from global (WT is <=32KB, L1/L2-hot) ----
    short8 bfrag[KSTEPS][4];
    #pragma unroll
    for (int ks = 0; ks < KSTEPS; ++ks)
        #pragma unroll
        for (int tn = 0; tn < 4; ++tn) {
            int n = wc * 64 + tn * 16 + l15;
            bfrag[ks][tn] = *(const short8*)(WT + (size_t)n * KP + ks * 32 + quad * 8);
        }

    floatx4 acc[4][2];
    #pragma unroll
    for (int tn = 0; tn < 4; ++tn)
        #pragma unroll
        for (int rt = 0; rt < 2; ++rt)
            acc[tn][rt] = (floatx4){0.f, 0.f, 0.f, 0.f};

    __syncthreads();

    #pragma unroll
    for (int ks = 0; ks < KSTEPS; ++ks) {
        short8 af[2];
        #pragma unroll
        for (int rt = 0; rt < 2; ++rt) {
            int m = wr * 32 + rt * 16 + l15;
            af[rt] = *(const short8*)&lds_a[m * 136 + ks * 32 + quad * 8];
        }
        #pragma unroll
        for (int tn = 0; tn < 4; ++tn)
            #pragma unroll
            for (int rt = 0; rt < 2; ++rt)
                acc[tn][rt] = __builtin_amdgcn_mfma_f32_16x16x32_bf16(
                    af[rt], bfrag[ks][tn], acc[tn][rt], 0, 0, 0);
    }

    // ---- epilogue: bias + SiLU (+ norm_src scale) + store (C/D: col=lane&15, row=quad*4+reg) ----
    #pragma unroll
    for (int tn = 0; tn < 4; ++tn) {
        int col = wc * 64 + tn * 16 + l15;
        float b = bias[col];
        #pragma unroll
        for (int rt = 0; rt < 2; ++rt) {
            #pragma unroll
            for (int r = 0; r < 4; ++r) {
                int row = rowbase + wr * 32 + rt * 16 + quad * 4 + r;
                if (row < nrows) {
                    float v = acc[tn][rt][r] + b;
                    if (DO_SILU) v = silu_f(v);
                    if (SCALE_NORM) v *= norm_src[row];
                    if (OUT_BF16)
                        ((unsigned short*)out_)[(size_t)row * 128 + col] = f2bf(v);
                    else
                        ((float*)out_)[(size_t)row * 128 + col] = v;
                }
            }
        }
    }
}

// ---------------- fp32 GEMM (kept for the small final matmul) ----------------
template<int K, bool DO_SILU>
__launch_bounds__(256)
__global__ void gemm_kernel(const float* __restrict__ in, const float* __restrict__ W,
                            const float* __restrict__ bias, float* __restrict__ out, int nrows) {
    __shared__ float wl[64 * HID];
    __shared__ float xl[32 * K];
    int t = threadIdx.x;
    int row0 = blockIdx.x * 32;

    for (int i = t; i < 32 * K; i += 256) {
        int r = i / K, k = i - r * K;
        int gr = row0 + r;
        xl[i] = (gr < nrows) ? in[(size_t)gr * K + k] : 0.0f;
    }

    int col = t & (HID - 1);
    int rg  = t >> 7;
    float acc[16];
    #pragma unroll
    for (int rr = 0; rr < 16; ++rr) acc[rr] = 0.0f;

    for (int c = 0; c < K; c += 64) {
        int kc = (K - c < 64) ? (K - c) : 64;
        __syncthreads();
        for (int i = t; i < kc * HID; i += 256) wl[i] = W[(size_t)c * HID + i];
        __syncthreads();
        for (int kk = 0; kk < kc; ++kk) {
            float w = wl[kk * HID + col];
            int k = c + kk;
            #pragma unroll
            for (int rr = 0; rr < 16; ++rr)
                acc[rr] += xl[(rg * 16 + rr) * K + k] * w;
        }
    }

    float b = bias[col];
    #pragma unroll
    for (int rr = 0; rr < 16; ++rr) {
        int r = row0 + rg * 16 + rr;
        if (r < nrows) {
            float v = acc[rr] + b;
            if (DO_SILU) v = silu_f(v);
            out[(size_t)r * HID + col] = v;
        }
    }
}

// ---------------- pooling: sorted graph_ids -> segmented sum, no atomics ----------------
__device__ __forceinline__ int lower_bound_gid(const int* __restrict__ gid, int val) {
    int lo = 0, hi = N_NODES;
    while (lo < hi) {
        int mid = (lo + hi) >> 1;
        if (gid[mid] < val) lo = mid + 1; else hi = mid;
    }
    return lo;
}

__global__ void pool_kernel(const float* __restrict__ h, const int* __restrict__ gid,
                            float* __restrict__ pooled) {
    int g = blockIdx.x;
    int t = threadIdx.x;   // 128 threads, one per column
    int beg = lower_bound_gid(gid, g);
    int end = lower_bound_gid(gid, g + 1);
    float s = 0.0f;
    for (int n = beg; n < end; ++n)
        s += h[(size_t)n * HID + t];
    pooled[(size_t)g * HID + t] = s;
}

extern "C" void kernel_launch(void* const* d_in, const int* in_sizes, int n_in,
                              void* d_out, int out_size, void* d_ws, size_t ws_size,
                              hipStream_t stream) {
    const float* x     = (const float*)d_in[0];
    const int*   src   = (const int*)  d_in[1];
    const int*   dst   = (const int*)  d_in[2];
    const int*   gid   = (const int*)  d_in[3];
    const float* w_in  = (const float*)d_in[4];
    const float* b_in  = (const float*)d_in[5];
    const float* gw    = (const float*)d_in[6];
    const float* gb    = (const float*)d_in[7];
    const float* w_out = (const float*)d_in[8];
    const float* b_out = (const float*)d_in[9];
    const float* w_ff  = (const float*)d_in[10];
    const float* b_ff  = (const float*)d_in[11];
    float* out = (float*)d_out;

    char* w = (char*)d_ws;
    size_t off = 0;
    auto alloc = [&](size_t bytes) { void* p = w + off; off += (bytes + 255) & ~(size_t)255; return p; };
    unsigned short* hb0 = (unsigned short*)alloc((size_t)N_NODES * HID * 2);  // bf16 h (conv loop)
    unsigned short* hb1 = (unsigned short*)alloc((size_t)N_NODES * HID * 2);  // bf16 agg
    float* h1       = (float*)alloc((size_t)N_NODES * HID * 4);               // fp32 pool input
    float* norm_src = (float*)alloc((size_t)N_NODES * 4);
    float* norm_dst = (float*)alloc((size_t)N_NODES * 4);
    int*   deg_out  = (int*)  alloc((size_t)N_NODES * 4);
    int*   deg_in   = (int*)  alloc((size_t)N_NODES * 4);
    int*   cursor   = (int*)  alloc((size_t)N_NODES * 4);
    int*   row_off  = (int*)  alloc((size_t)(N_NODES + 1) * 4);
    int*   esrc     = (int*)  alloc((size_t)N_EDGES * 4);
    int*   bsums    = (int*)  alloc(1024 * 4);
    float* pooled   = (float*)alloc((size_t)N_GRAPHS * HID * 4);
    unsigned short* wtin  = (unsigned short*)alloc(128 * 96 * 2);
    unsigned short* wtg   = (unsigned short*)alloc(3 * 128 * 128 * 2);
    unsigned short* wtout = (unsigned short*)alloc(128 * 128 * 2);

    const int NB_NODES = (N_NODES + 255) / 256;   // 782
    const int NB_EDGES = (N_EDGES + 255) / 256;   // 6250

    // degrees + norms + CSR (once; shared by all 3 convs) + weight prep
    hipMemsetAsync(deg_out, 0, (size_t)N_NODES * 4, stream);
    hipMemsetAsync(deg_in,  0, (size_t)N_NODES * 4, stream);
    hipMemsetAsync(cursor,  0, (size_t)N_NODES * 4, stream);
    deg_kernel<<<NB_EDGES, 256, 0, stream>>>(src, dst, deg_out, deg_in);
    norm_kernel<<<NB_NODES, 256, 0, stream>>>(deg_out, deg_in, norm_src, norm_dst);
    scan1_kernel<<<NB_NODES, 256, 0, stream>>>(deg_in, row_off, bsums);
    scan2_kernel<<<1, 1024, 0, stream>>>(bsums, NB_NODES);
    scan3_kernel<<<NB_NODES, 256, 0, stream>>>(row_off, bsums);
    fill_kernel<<<NB_EDGES, 256, 0, stream>>>(src, dst, row_off, cursor, esrc);
    wprep_kernel<<<(128 * 96 + 4 * 128 * 128 + 255) / 256, 256, 0, stream>>>(
        w_in, gw, w_out, wtin, wtg, wtout);

    const int NB_M = (N_NODES + 63) / 64;   // 3125

    // h = silu(x @ w_in + b_in) * norm_src   -> bf16
    mfma_gemm<IN_F, 96, true, false, true, true><<<NB_M, 256, 0, stream>>>(
        x, wtin, b_in, norm_src, hb0, N_NODES);

    // 3 graph convs; conv0/1 outputs feed SpMM (scaled), conv2 output feeds w_out GEMM (unscaled)
    spmm_bf16<<<(N_NODES + 15) / 16, 256, 0, stream>>>(hb0, esrc, row_off, norm_dst, hb1);
    mfma_gemm<HID, 128, true, true, true, true><<<NB_M, 256, 0, stream>>>(
        hb1, wtg + 0 * HID * HID, gb + 0 * HID, norm_src, hb0, N_NODES);

    spmm_bf16<<<(N_NODES + 15) / 16, 256, 0, stream>>>(hb0, esrc, row_off, norm_dst, hb1);
    mfma_gemm<HID, 128, true, true, true, true><<<NB_M, 256, 0, stream>>>(
        hb1, wtg + 1 * HID * HID, gb + 1 * HID, norm_src, hb0, N_NODES);

    spmm_bf16<<<(N_NODES + 15) / 16, 256, 0, stream>>>(hb0, esrc, row_off, norm_dst, hb1);
    mfma_gemm<HID, 128, true, true, true, false><<<NB_M, 256, 0, stream>>>(
        hb1, wtg + 2 * HID * HID, gb + 2 * HID, norm_src, hb0, N_NODES);

    // h1 = silu(h @ w_out + b_out)  -> fp32 (pool input kept full precision)
    mfma_gemm<HID, 128, true, true, false, false><<<NB_M, 256, 0, stream>>>(
        hb0, wtout, b_out, norm_src, h1, N_NODES);

    // pooled = segment_sum(h1, gid)  -- gid sorted, segmented, no atomics
    pool_kernel<<<N_GRAPHS, HID, 0, stream>>>(h1, gid, pooled);

    // out = pooled @ w_ff + b_ff   (small, keep fp32 for accuracy)
    gemm_kernel<HID, false><<<(N_GRAPHS + 31) / 32, 256, 0, stream>>>(pooled, w_ff, b_ff, out, N_GRAPHS);
}

// Round 4
// 771.575 us; speedup vs baseline: 2.8114x; 1.2076x over previous
//
#include <hip/hip_runtime.h>
#include <math.h>

#define N_NODES  200000
#define N_EDGES  1600000
#define N_GRAPHS 10000
#define IN_F     74
#define HID      128
#define DEPTH    3

#define NBUCK 391          // ceil(N_NODES / 512): bucket = id >> 9
#define G1    512          // blocks in count/scatter pass
#define CHUNK 3125         // N_EDGES / G1 (exact)
#define NTOT  (NBUCK * G1) // 200192 scan elements

typedef __attribute__((ext_vector_type(8))) short short8;
typedef __attribute__((ext_vector_type(8))) unsigned short ushort8v;
typedef __attribute__((ext_vector_type(4))) float floatx4;

__device__ __forceinline__ float silu_f(float x) {
    return x / (1.0f + __expf(-x));
}

__device__ __forceinline__ unsigned short f2bf(float f) {
    union { float f; unsigned int u; } v; v.f = f;
    unsigned int r = (v.u + 0x7fff + ((v.u >> 16) & 1)) >> 16;   // RNE
    return (unsigned short)r;
}

__device__ __forceinline__ float bf2f(unsigned short u) {
    union { unsigned int u; float f; } v; v.u = ((unsigned int)u) << 16;
    return v.f;
}

// ================= atomic-free CSR build (radix partition by id>>9) =================

// per-(bucket,block) histograms of dst and src, LDS atomics only
__global__ void count_kernel(const int* __restrict__ src, const int* __restrict__ dst,
                             int* __restrict__ cnt_d, int* __restrict__ cnt_s) {
    __shared__ int hd[NBUCK], hs[NBUCK];
    int t = threadIdx.x, b = blockIdx.x;
    for (int i = t; i < NBUCK; i += 256) { hd[i] = 0; hs[i] = 0; }
    __syncthreads();
    int e0 = b * CHUNK;
    for (int i = t; i < CHUNK; i += 256) {
        int e = e0 + i;
        atomicAdd(&hd[dst[e] >> 9], 1);
        atomicAdd(&hs[src[e] >> 9], 1);
    }
    __syncthreads();
    for (int i = t; i < NBUCK; i += 256) {
        cnt_d[i * G1 + b] = hd[i];
        cnt_s[i * G1 + b] = hs[i];
    }
}

// generic exclusive scan (3 kernels), n <= 256*1024
__global__ void gscan1(const int* __restrict__ in, int* __restrict__ out,
                       int* __restrict__ bsums, int n) {
    __shared__ int a[256], b2[256];
    int t = threadIdx.x;
    int i = blockIdx.x * 256 + t;
    a[t] = (i < n) ? in[i] : 0;
    __syncthreads();
    int* s = a; int* d = b2;
    #pragma unroll
    for (int off = 1; off < 256; off <<= 1) {
        int v = s[t];
        if (t >= off) v += s[t - off];
        d[t] = v;
        __syncthreads();
        int* tmp = s; s = d; d = tmp;
    }
    if (i < n) out[i] = (t ? s[t - 1] : 0);
    if (t == 255) bsums[blockIdx.x] = s[255];
}

__global__ void gscan2(int* __restrict__ bsums, int nb) {
    __shared__ int a[1024], b[1024];
    int t = threadIdx.x;
    a[t] = (t < nb) ? bsums[t] : 0;
    __syncthreads();
    int* s = a; int* d = b;
    for (int off = 1; off < 1024; off <<= 1) {
        int v = s[t];
        if (t >= off) v += s[t - off];
        d[t] = v;
        __syncthreads();
        int* tmp = s; s = d; d = tmp;
    }
    if (t < nb) bsums[t] = s[t];
}

__global__ void gscan3(int* __restrict__ out, const int* __restrict__ bsums, int n) {
    int i = blockIdx.x * 256 + threadIdx.x;
    if (i < n && blockIdx.x > 0) out[i] += bsums[blockIdx.x - 1];
}

// scatter edges into bucket-partitioned buffers; each (bucket,block) range written sequentially
__global__ void scatter_kernel(const int* __restrict__ src, const int* __restrict__ dst,
                               const int* __restrict__ offs_d, const int* __restrict__ offs_s,
                               int2* __restrict__ ebuf, int* __restrict__ sbuf) {
    __shared__ int cd[NBUCK], cs[NBUCK];
    int t = threadIdx.x, b = blockIdx.x;
    for (int i = t; i < NBUCK; i += 256) {
        cd[i] = offs_d[i * G1 + b];
        cs[i] = offs_s[i * G1 + b];
    }
    __syncthreads();
    int e0 = b * CHUNK;
    for (int i = t; i < CHUNK; i += 256) {
        int e = e0 + i;
        int d = dst[e], s = src[e];
        int pd = atomicAdd(&cd[d >> 9], 1);
        int2 p; p.x = d; p.y = s;
        ebuf[pd] = p;
        int ps = atomicAdd(&cs[s >> 9], 1);
        sbuf[ps] = s;
    }
}

// per dst-bucket: deg -> row_off + norm_dst + final esrc (all LDS atomics)
__global__ __launch_bounds__(512)
void csr_kernel(const int2* __restrict__ ebuf, const int* __restrict__ offs_d,
                int* __restrict__ row_off, int* __restrict__ esrc,
                float* __restrict__ norm_dst) {
    __shared__ int deg[512];
    __shared__ int sa[512], sb[512];
    int k = blockIdx.x, t = threadIdx.x;
    int base = k << 9;
    int estart = offs_d[k * G1];
    int eend = (k + 1 < NBUCK) ? offs_d[(k + 1) * G1] : N_EDGES;
    deg[t] = 0;
    __syncthreads();
    for (int e = estart + t; e < eend; e += 512)
        atomicAdd(&deg[ebuf[e].x - base], 1);
    __syncthreads();
    sa[t] = deg[t];
    __syncthreads();
    int* ps = sa; int* pd = sb;
    #pragma unroll
    for (int off = 1; off < 512; off <<= 1) {
        int v = ps[t];
        if (t >= off) v += ps[t - off];
        pd[t] = v;
        __syncthreads();
        int* tmp = ps; ps = pd; pd = tmp;
    }
    int excl = t ? ps[t - 1] : 0;
    int n = base + t;
    if (n <= N_NODES) row_off[n] = estart + excl;
    if (n < N_NODES)  norm_dst[n] = rsqrtf(fmaxf((float)deg[t], 1.0f));
    __syncthreads();
    pd[t] = estart + excl;   // cursors (pd is the free buffer)
    __syncthreads();
    for (int e = estart + t; e < eend; e += 512) {
        int2 ed = ebuf[e];
        int pos = atomicAdd(&pd[ed.x - base], 1);
        esrc[pos] = ed.y;
    }
}

// per src-bucket: out-degree -> norm_src
__global__ __launch_bounds__(512)
void degsrc_kernel(const int* __restrict__ sbuf, const int* __restrict__ offs_s,
                   float* __restrict__ norm_src) {
    __shared__ int deg[512];
    int k = blockIdx.x, t = threadIdx.x;
    int base = k << 9;
    int estart = offs_s[k * G1];
    int eend = (k + 1 < NBUCK) ? offs_s[(k + 1) * G1] : N_EDGES;
    deg[t] = 0;
    __syncthreads();
    for (int e = estart + t; e < eend; e += 512)
        atomicAdd(&deg[sbuf[e] - base], 1);
    __syncthreads();
    int n = base + t;
    if (n < N_NODES) norm_src[n] = rsqrtf(fmaxf((float)deg[t], 1.0f));
}

// ================= pull-based SpMM, bf16 in/out =================
// h is pre-scaled by norm_src (folded into producer GEMM epilogue).
__global__ void spmm_bf16(const unsigned short* __restrict__ h, const int* __restrict__ esrc,
                          const int* __restrict__ row_off,
                          const float* __restrict__ norm_dst,
                          unsigned short* __restrict__ agg) {
    int t = threadIdx.x;
    int node = blockIdx.x * 16 + (t >> 4);
    if (node >= N_NODES) return;
    int lane = t & 15;
    int beg = row_off[node], end = row_off[node + 1];
    float acc[8];
    #pragma unroll
    for (int q = 0; q < 8; ++q) acc[q] = 0.0f;

    int j = beg;
    for (; j + 3 < end; j += 4) {
        int s0 = esrc[j], s1 = esrc[j + 1], s2 = esrc[j + 2], s3 = esrc[j + 3];
        ushort8v v0 = *(const ushort8v*)(h + (size_t)s0 * HID + lane * 8);
        ushort8v v1 = *(const ushort8v*)(h + (size_t)s1 * HID + lane * 8);
        ushort8v v2 = *(const ushort8v*)(h + (size_t)s2 * HID + lane * 8);
        ushort8v v3 = *(const ushort8v*)(h + (size_t)s3 * HID + lane * 8);
        #pragma unroll
        for (int q = 0; q < 8; ++q)
            acc[q] += (bf2f(v0[q]) + bf2f(v1[q])) + (bf2f(v2[q]) + bf2f(v3[q]));
    }
    for (; j < end; ++j) {
        int s0 = esrc[j];
        ushort8v v0 = *(const ushort8v*)(h + (size_t)s0 * HID + lane * 8);
        #pragma unroll
        for (int q = 0; q < 8; ++q)
            acc[q] += bf2f(v0[q]);
    }

    float nd = norm_dst[node];
    ushort8v o;
    #pragma unroll
    for (int q = 0; q < 8; ++q) o[q] = f2bf(acc[q] * nd);
    *(ushort8v*)(agg + (size_t)node * HID + lane * 8) = o;
}

// ================= weight prep =================
__global__ void wprep_kernel(const float* __restrict__ w_in, const float* __restrict__ gw,
                             const float* __restrict__ w_out,
                             unsigned short* __restrict__ wtin,   // [128][96]
                             unsigned short* __restrict__ wtg,    // [3][128][128]
                             unsigned short* __restrict__ wtout)  // [128][128]
{
    int i = blockIdx.x * 256 + threadIdx.x;
    if (i < 128 * 96) {
        int n = i / 96, k = i - n * 96;
        wtin[i] = (k < IN_F) ? f2bf(w_in[k * 128 + n]) : (unsigned short)0;
    } else if (i < 128 * 96 + 3 * 128 * 128) {
        int j = i - 128 * 96;
        int layer = j / 16384, r = j - layer * 16384;
        int n = r >> 7, k = r & 127;
        wtg[j] = f2bf(gw[((size_t)layer * 128 + k) * 128 + n]);
    } else if (i < 128 * 96 + 3 * 128 * 128 + 128 * 128) {
        int j = i - (128 * 96 + 3 * 128 * 128);
        int n = j >> 7, k = j & 127;
        wtout[j] = f2bf(w_out[k * 128 + n]);
    }
}

// ================= bf16 MFMA GEMM =================
// Block: 256 threads = 4 waves; block tile 64 rows x 128 cols; wave tile 32 rows x 64 cols.
template<int K_IN, int KP, bool DO_SILU, bool A_BF16, bool OUT_BF16, bool SCALE_NORM>
__launch_bounds__(256)
__global__ void mfma_gemm(const void* __restrict__ in_, const unsigned short* __restrict__ WT,
                          const float* __restrict__ bias, const float* __restrict__ norm_src,
                          void* __restrict__ out_, int nrows) {
    constexpr int KSTEPS = KP / 32;
    __shared__ unsigned short lds_a[64 * 136];   // +8 pad: 2-way bank alias only (free)
    const int t = threadIdx.x;
    const int rowbase = blockIdx.x * 64;

    if constexpr (A_BF16) {
        const unsigned short* in = (const unsigned short*)in_;
        #pragma unroll
        for (int j = 0; j < 4; ++j) {
            int e = j * 256 + t;
            int r = e >> 4;
            int c = (e & 15) * 8;
            int row = rowbase + r;
            ushort8v u = {0,0,0,0,0,0,0,0};
            if (row < nrows) u = *(const ushort8v*)(in + (size_t)row * K_IN + c);
            *(ushort8v*)&lds_a[r * 136 + c] = u;
        }
    } else {
        const float* in = (const float*)in_;
        for (int i = t; i < 64 * KP; i += 256) {
            int r = i / KP, k = i - r * KP;
            int row = rowbase + r;
            float v = (k < K_IN && row < nrows) ? in[(size_t)row * K_IN + k] : 0.0f;
            lds_a[r * 136 + k] = f2bf(v);
        }
    }

    const int lane = t & 63;
    const int w  = t >> 6;
    const int wr = w & 1;
    const int wc = w >> 1;
    const int l15 = lane & 15, quad = lane >> 4;

    short8 bfrag[KSTEPS][4];
    #pragma unroll
    for (int ks = 0; ks < KSTEPS; ++ks)
        #pragma unroll
        for (int tn = 0; tn < 4; ++tn) {
            int n = wc * 64 + tn * 16 + l15;
            bfrag[ks][tn] = *(const short8*)(WT + (size_t)n * KP + ks * 32 + quad * 8);
        }

    floatx4 acc[4][2];
    #pragma unroll
    for (int tn = 0; tn < 4; ++tn)
        #pragma unroll
        for (int rt = 0; rt < 2; ++rt)
            acc[tn][rt] = (floatx4){0.f, 0.f, 0.f, 0.f};

    __syncthreads();

    #pragma unroll
    for (int ks = 0; ks < KSTEPS; ++ks) {
        short8 af[2];
        #pragma unroll
        for (int rt = 0; rt < 2; ++rt) {
            int m = wr * 32 + rt * 16 + l15;
            af[rt] = *(const short8*)&lds_a[m * 136 + ks * 32 + quad * 8];
        }
        #pragma unroll
        for (int tn = 0; tn < 4; ++tn)
            #pragma unroll
            for (int rt = 0; rt < 2; ++rt)
                acc[tn][rt] = __builtin_amdgcn_mfma_f32_16x16x32_bf16(
                    af[rt], bfrag[ks][tn], acc[tn][rt], 0, 0, 0);
    }

    #pragma unroll
    for (int tn = 0; tn < 4; ++tn) {
        int col = wc * 64 + tn * 16 + l15;
        float b = bias[col];
        #pragma unroll
        for (int rt = 0; rt < 2; ++rt) {
            #pragma unroll
            for (int r = 0; r < 4; ++r) {
                int row = rowbase + wr * 32 + rt * 16 + quad * 4 + r;
                if (row < nrows) {
                    float v = acc[tn][rt][r] + b;
                    if (DO_SILU) v = silu_f(v);
                    if (SCALE_NORM) v *= norm_src[row];
                    if (OUT_BF16)
                        ((unsigned short*)out_)[(size_t)row * 128 + col] = f2bf(v);
                    else
                        ((float*)out_)[(size_t)row * 128 + col] = v;
                }
            }
        }
    }
}

// ================= fp32 GEMM (small final matmul) =================
template<int K, bool DO_SILU>
__launch_bounds__(256)
__global__ void gemm_kernel(const float* __restrict__ in, const float* __restrict__ W,
                            const float* __restrict__ bias, float* __restrict__ out, int nrows) {
    __shared__ float wl[64 * HID];
    __shared__ float xl[32 * K];
    int t = threadIdx.x;
    int row0 = blockIdx.x * 32;

    for (int i = t; i < 32 * K; i += 256) {
        int r = i / K, k = i - r * K;
        int gr = row0 + r;
        xl[i] = (gr < nrows) ? in[(size_t)gr * K + k] : 0.0f;
    }

    int col = t & (HID - 1);
    int rg  = t >> 7;
    float acc[16];
    #pragma unroll
    for (int rr = 0; rr < 16; ++rr) acc[rr] = 0.0f;

    for (int c = 0; c < K; c += 64) {
        int kc = (K - c < 64) ? (K - c) : 64;
        __syncthreads();
        for (int i = t; i < kc * HID; i += 256) wl[i] = W[(size_t)c * HID + i];
        __syncthreads();
        for (int kk = 0; kk < kc; ++kk) {
            float w = wl[kk * HID + col];
            int k = c + kk;
            #pragma unroll
            for (int rr = 0; rr < 16; ++rr)
                acc[rr] += xl[(rg * 16 + rr) * K + k] * w;
        }
    }

    float b = bias[col];
    #pragma unroll
    for (int rr = 0; rr < 16; ++rr) {
        int r = row0 + rg * 16 + rr;
        if (r < nrows) {
            float v = acc[rr] + b;
            if (DO_SILU) v = silu_f(v);
            out[(size_t)r * HID + col] = v;
        }
    }
}

// ================= pooling: sorted graph_ids -> segmented sum =================
__device__ __forceinline__ int lower_bound_gid(const int* __restrict__ gid, int val) {
    int lo = 0, hi = N_NODES;
    while (lo < hi) {
        int mid = (lo + hi) >> 1;
        if (gid[mid] < val) lo = mid + 1; else hi = mid;
    }
    return lo;
}

__global__ void pool_kernel(const unsigned short* __restrict__ h, const int* __restrict__ gid,
                            float* __restrict__ pooled) {
    int g = blockIdx.x;
    int t = threadIdx.x;   // 128 threads, one per column
    int beg = lower_bound_gid(gid, g);
    int end = lower_bound_gid(gid, g + 1);
    float s = 0.0f;
    for (int n = beg; n < end; ++n)
        s += bf2f(h[(size_t)n * HID + t]);
    pooled[(size_t)g * HID + t] = s;
}

extern "C" void kernel_launch(void* const* d_in, const int* in_sizes, int n_in,
                              void* d_out, int out_size, void* d_ws, size_t ws_size,
                              hipStream_t stream) {
    const float* x     = (const float*)d_in[0];
    const int*   src   = (const int*)  d_in[1];
    const int*   dst   = (const int*)  d_in[2];
    const int*   gid   = (const int*)  d_in[3];
    const float* w_in  = (const float*)d_in[4];
    const float* b_in  = (const float*)d_in[5];
    const float* gw    = (const float*)d_in[6];
    const float* gb    = (const float*)d_in[7];
    const float* w_out = (const float*)d_in[8];
    const float* b_out = (const float*)d_in[9];
    const float* w_ff  = (const float*)d_in[10];
    const float* b_ff  = (const float*)d_in[11];
    float* out = (float*)d_out;

    char* w = (char*)d_ws;
    size_t off = 0;
    auto alloc = [&](size_t bytes) { void* p = w + off; off += (bytes + 255) & ~(size_t)255; return p; };
    unsigned short* hb0 = (unsigned short*)alloc((size_t)N_NODES * HID * 2);
    unsigned short* hb1 = (unsigned short*)alloc((size_t)N_NODES * HID * 2);
    float* norm_src = (float*)alloc((size_t)N_NODES * 4);
    float* norm_dst = (float*)alloc((size_t)N_NODES * 4);
    int*   row_off  = (int*)  alloc((size_t)(N_NODES + 1) * 4);
    int*   esrc     = (int*)  alloc((size_t)N_EDGES * 4);
    int2*  ebuf     = (int2*) alloc((size_t)N_EDGES * 8);
    int*   sbuf     = (int*)  alloc((size_t)N_EDGES * 4);
    int*   cnt_d    = (int*)  alloc((size_t)NTOT * 4);
    int*   cnt_s    = (int*)  alloc((size_t)NTOT * 4);
    int*   offs_d   = (int*)  alloc((size_t)NTOT * 4);
    int*   offs_s   = (int*)  alloc((size_t)NTOT * 4);
    int*   bsums    = (int*)  alloc(1024 * 4);
    float* pooled   = (float*)alloc((size_t)N_GRAPHS * HID * 4);
    unsigned short* wtin  = (unsigned short*)alloc(128 * 96 * 2);
    unsigned short* wtg   = (unsigned short*)alloc(3 * 128 * 128 * 2);
    unsigned short* wtout = (unsigned short*)alloc(128 * 128 * 2);

    const int NB_SCAN = NTOT / 256;   // 782 exactly

    // ---- CSR build, no global atomics ----
    count_kernel<<<G1, 256, 0, stream>>>(src, dst, cnt_d, cnt_s);
    gscan1<<<NB_SCAN, 256, 0, stream>>>(cnt_d, offs_d, bsums, NTOT);
    gscan2<<<1, 1024, 0, stream>>>(bsums, NB_SCAN);
    gscan3<<<NB_SCAN, 256, 0, stream>>>(offs_d, bsums, NTOT);
    gscan1<<<NB_SCAN, 256, 0, stream>>>(cnt_s, offs_s, bsums, NTOT);
    gscan2<<<1, 1024, 0, stream>>>(bsums, NB_SCAN);
    gscan3<<<NB_SCAN, 256, 0, stream>>>(offs_s, bsums, NTOT);
    scatter_kernel<<<G1, 256, 0, stream>>>(src, dst, offs_d, offs_s, ebuf, sbuf);
    csr_kernel<<<NBUCK, 512, 0, stream>>>(ebuf, offs_d, row_off, esrc, norm_dst);
    degsrc_kernel<<<NBUCK, 512, 0, stream>>>(sbuf, offs_s, norm_src);

    wprep_kernel<<<(128 * 96 + 4 * 128 * 128 + 255) / 256, 256, 0, stream>>>(
        w_in, gw, w_out, wtin, wtg, wtout);

    const int NB_M = (N_NODES + 63) / 64;   // 3125

    // h = silu(x @ w_in + b_in) * norm_src   -> bf16
    mfma_gemm<IN_F, 96, true, false, true, true><<<NB_M, 256, 0, stream>>>(
        x, wtin, b_in, norm_src, hb0, N_NODES);

    // 3 graph convs
    spmm_bf16<<<(N_NODES + 15) / 16, 256, 0, stream>>>(hb0, esrc, row_off, norm_dst, hb1);
    mfma_gemm<HID, 128, true, true, true, true><<<NB_M, 256, 0, stream>>>(
        hb1, wtg + 0 * HID * HID, gb + 0 * HID, norm_src, hb0, N_NODES);

    spmm_bf16<<<(N_NODES + 15) / 16, 256, 0, stream>>>(hb0, esrc, row_off, norm_dst, hb1);
    mfma_gemm<HID, 128, true, true, true, true><<<NB_M, 256, 0, stream>>>(
        hb1, wtg + 1 * HID * HID, gb + 1 * HID, norm_src, hb0, N_NODES);

    spmm_bf16<<<(N_NODES + 15) / 16, 256, 0, stream>>>(hb0, esrc, row_off, norm_dst, hb1);
    mfma_gemm<HID, 128, true, true, true, false><<<NB_M, 256, 0, stream>>>(
        hb1, wtg + 2 * HID * HID, gb + 2 * HID, norm_src, hb0, N_NODES);

    // h = silu(h @ w_out + b_out) -> bf16 (into hb1)
    mfma_gemm<HID, 128, true, true, true, false><<<NB_M, 256, 0, stream>>>(
        hb0, wtout, b_out, norm_src, hb1, N_NODES);

    // pooled = segment_sum(h, gid)
    pool_kernel<<<N_GRAPHS, HID, 0, stream>>>(hb1, gid, pooled);

    // out = pooled @ w_ff + b_ff (fp32)
    gemm_kernel<HID, false><<<(N_GRAPHS + 31) / 32, 256, 0, stream>>>(pooled, w_ff, b_ff, out, N_GRAPHS);
}

// Round 5
// 700.986 us; speedup vs baseline: 3.0945x; 1.1007x over previous
//
#include <hip/hip_runtime.h>
#include <math.h>

#define N_NODES  200000
#define N_EDGES  1600000
#define N_GRAPHS 10000
#define IN_F     74
#define HID      128
#define DEPTH    3

#define NBUCK 391          // ceil(N_NODES / 512): bucket = id >> 9
#define G1    512          // blocks in count/scatter pass
#define CHUNK 3125         // N_EDGES / G1 (exact)
#define NTOT  (NBUCK * G1) // 200192 scan elements

typedef __attribute__((ext_vector_type(8))) short short8;
typedef __attribute__((ext_vector_type(8))) unsigned short ushort8v;
typedef __attribute__((ext_vector_type(4))) float floatx4;

__device__ __forceinline__ float silu_f(float x) {
    return x / (1.0f + __expf(-x));
}

__device__ __forceinline__ unsigned short f2bf(float f) {
    union { float f; unsigned int u; } v; v.f = f;
    unsigned int r = (v.u + 0x7fff + ((v.u >> 16) & 1)) >> 16;   // RNE
    return (unsigned short)r;
}

__device__ __forceinline__ float bf2f(unsigned short u) {
    union { unsigned int u; float f; } v; v.u = ((unsigned int)u) << 16;
    return v.f;
}

// ================= atomic-free CSR build (radix partition by id>>9) =================

__global__ void count_kernel(const int* __restrict__ src, const int* __restrict__ dst,
                             int* __restrict__ cnt_d, int* __restrict__ cnt_s) {
    __shared__ int hd[NBUCK], hs[NBUCK];
    int t = threadIdx.x, b = blockIdx.x;
    for (int i = t; i < NBUCK; i += 256) { hd[i] = 0; hs[i] = 0; }
    __syncthreads();
    int e0 = b * CHUNK;
    for (int i = t; i < CHUNK; i += 256) {
        int e = e0 + i;
        atomicAdd(&hd[dst[e] >> 9], 1);
        atomicAdd(&hs[src[e] >> 9], 1);
    }
    __syncthreads();
    for (int i = t; i < NBUCK; i += 256) {
        cnt_d[i * G1 + b] = hd[i];
        cnt_s[i * G1 + b] = hs[i];
    }
}

__global__ void gscan1(const int* __restrict__ in, int* __restrict__ out,
                       int* __restrict__ bsums, int n) {
    __shared__ int a[256], b2[256];
    int t = threadIdx.x;
    int i = blockIdx.x * 256 + t;
    a[t] = (i < n) ? in[i] : 0;
    __syncthreads();
    int* s = a; int* d = b2;
    #pragma unroll
    for (int off = 1; off < 256; off <<= 1) {
        int v = s[t];
        if (t >= off) v += s[t - off];
        d[t] = v;
        __syncthreads();
        int* tmp = s; s = d; d = tmp;
    }
    if (i < n) out[i] = (t ? s[t - 1] : 0);
    if (t == 255) bsums[blockIdx.x] = s[255];
}

__global__ void gscan2(int* __restrict__ bsums, int nb) {
    __shared__ int a[1024], b[1024];
    int t = threadIdx.x;
    a[t] = (t < nb) ? bsums[t] : 0;
    __syncthreads();
    int* s = a; int* d = b;
    for (int off = 1; off < 1024; off <<= 1) {
        int v = s[t];
        if (t >= off) v += s[t - off];
        d[t] = v;
        __syncthreads();
        int* tmp = s; s = d; d = tmp;
    }
    if (t < nb) bsums[t] = s[t];
}

__global__ void gscan3(int* __restrict__ out, const int* __restrict__ bsums, int n) {
    int i = blockIdx.x * 256 + threadIdx.x;
    if (i < n && blockIdx.x > 0) out[i] += bsums[blockIdx.x - 1];
}

__global__ void scatter_kernel(const int* __restrict__ src, const int* __restrict__ dst,
                               const int* __restrict__ offs_d, const int* __restrict__ offs_s,
                               int2* __restrict__ ebuf, int* __restrict__ sbuf) {
    __shared__ int cd[NBUCK], cs[NBUCK];
    int t = threadIdx.x, b = blockIdx.x;
    for (int i = t; i < NBUCK; i += 256) {
        cd[i] = offs_d[i * G1 + b];
        cs[i] = offs_s[i * G1 + b];
    }
    __syncthreads();
    int e0 = b * CHUNK;
    for (int i = t; i < CHUNK; i += 256) {
        int e = e0 + i;
        int d = dst[e], s = src[e];
        int pd = atomicAdd(&cd[d >> 9], 1);
        int2 p; p.x = d; p.y = s;
        ebuf[pd] = p;
        int ps = atomicAdd(&cs[s >> 9], 1);
        sbuf[ps] = s;
    }
}

__global__ __launch_bounds__(512)
void csr_kernel(const int2* __restrict__ ebuf, const int* __restrict__ offs_d,
                int* __restrict__ row_off, int* __restrict__ esrc,
                float* __restrict__ norm_dst) {
    __shared__ int deg[512];
    __shared__ int sa[512], sb[512];
    int k = blockIdx.x, t = threadIdx.x;
    int base = k << 9;
    int estart = offs_d[k * G1];
    int eend = (k + 1 < NBUCK) ? offs_d[(k + 1) * G1] : N_EDGES;
    deg[t] = 0;
    __syncthreads();
    for (int e = estart + t; e < eend; e += 512)
        atomicAdd(&deg[ebuf[e].x - base], 1);
    __syncthreads();
    sa[t] = deg[t];
    __syncthreads();
    int* ps = sa; int* pd = sb;
    #pragma unroll
    for (int off = 1; off < 512; off <<= 1) {
        int v = ps[t];
        if (t >= off) v += ps[t - off];
        pd[t] = v;
        __syncthreads();
        int* tmp = ps; ps = pd; pd = tmp;
    }
    int excl = t ? ps[t - 1] : 0;
    int n = base + t;
    if (n <= N_NODES) row_off[n] = estart + excl;
    if (n < N_NODES)  norm_dst[n] = rsqrtf(fmaxf((float)deg[t], 1.0f));
    __syncthreads();
    pd[t] = estart + excl;
    __syncthreads();
    for (int e = estart + t; e < eend; e += 512) {
        int2 ed = ebuf[e];
        int pos = atomicAdd(&pd[ed.x - base], 1);
        esrc[pos] = ed.y;
    }
}

__global__ __launch_bounds__(512)
void degsrc_kernel(const int* __restrict__ sbuf, const int* __restrict__ offs_s,
                   float* __restrict__ norm_src) {
    __shared__ int deg[512];
    int k = blockIdx.x, t = threadIdx.x;
    int base = k << 9;
    int estart = offs_s[k * G1];
    int eend = (k + 1 < NBUCK) ? offs_s[(k + 1) * G1] : N_EDGES;
    deg[t] = 0;
    __syncthreads();
    for (int e = estart + t; e < eend; e += 512)
        atomicAdd(&deg[sbuf[e] - base], 1);
    __syncthreads();
    int n = base + t;
    if (n < N_NODES) norm_src[n] = rsqrtf(fmaxf((float)deg[t], 1.0f));
}

// ================= weight prep =================
__global__ void wprep_kernel(const float* __restrict__ w_in, const float* __restrict__ gw,
                             const float* __restrict__ w_out,
                             unsigned short* __restrict__ wtin,   // [128][96]
                             unsigned short* __restrict__ wtg,    // [3][128][128]
                             unsigned short* __restrict__ wtout)  // [128][128]
{
    int i = blockIdx.x * 256 + threadIdx.x;
    if (i < 128 * 96) {
        int n = i / 96, k = i - n * 96;
        wtin[i] = (k < IN_F) ? f2bf(w_in[k * 128 + n]) : (unsigned short)0;
    } else if (i < 128 * 96 + 3 * 128 * 128) {
        int j = i - 128 * 96;
        int layer = j / 16384, r = j - layer * 16384;
        int n = r >> 7, k = r & 127;
        wtg[j] = f2bf(gw[((size_t)layer * 128 + k) * 128 + n]);
    } else if (i < 128 * 96 + 3 * 128 * 128 + 128 * 128) {
        int j = i - (128 * 96 + 3 * 128 * 128);
        int n = j >> 7, k = j & 127;
        wtout[j] = f2bf(w_out[k * 128 + n]);
    }
}

// ================= fused conv: gather(SpMM) -> MFMA GEMM -> silu (+norm_src) =================
// Block: 256 threads, 64 dst nodes. h is bf16 pre-scaled by norm_src.
// N_NODES % 64 == 0, so no row bounds checks.
template<bool SCALE_NORM>
__launch_bounds__(256)
__global__ void fused_conv(const unsigned short* __restrict__ h,
                           const int* __restrict__ esrc, const int* __restrict__ row_off,
                           const float* __restrict__ norm_dst,
                           const unsigned short* __restrict__ WT,   // [128][128]
                           const float* __restrict__ bias, const float* __restrict__ norm_src,
                           unsigned short* __restrict__ out) {
    __shared__ unsigned short lds_a[64 * 136];   // A tile (also reused for C repack)
    const int t = threadIdx.x;
    const int rowbase = blockIdx.x * 64;
    const int grp = t >> 4;          // 0..15
    const int lane16 = t & 15;

    // ---- phase 1: gather agg rows (bf16) directly into LDS ----
    #pragma unroll
    for (int g = 0; g < 4; ++g) {
        int r = g * 16 + grp;
        int node = rowbase + r;
        int beg = row_off[node], end = row_off[node + 1];
        float acc[8];
        #pragma unroll
        for (int q = 0; q < 8; ++q) acc[q] = 0.0f;
        int j = beg;
        for (; j + 3 < end; j += 4) {
            int s0 = esrc[j], s1 = esrc[j + 1], s2 = esrc[j + 2], s3 = esrc[j + 3];
            ushort8v v0 = *(const ushort8v*)(h + (size_t)s0 * HID + lane16 * 8);
            ushort8v v1 = *(const ushort8v*)(h + (size_t)s1 * HID + lane16 * 8);
            ushort8v v2 = *(const ushort8v*)(h + (size_t)s2 * HID + lane16 * 8);
            ushort8v v3 = *(const ushort8v*)(h + (size_t)s3 * HID + lane16 * 8);
            #pragma unroll
            for (int q = 0; q < 8; ++q)
                acc[q] += (bf2f(v0[q]) + bf2f(v1[q])) + (bf2f(v2[q]) + bf2f(v3[q]));
        }
        for (; j < end; ++j) {
            int s0 = esrc[j];
            ushort8v v0 = *(const ushort8v*)(h + (size_t)s0 * HID + lane16 * 8);
            #pragma unroll
            for (int q = 0; q < 8; ++q)
                acc[q] += bf2f(v0[q]);
        }
        float nd = norm_dst[node];
        ushort8v o;
        #pragma unroll
        for (int q = 0; q < 8; ++q) o[q] = f2bf(acc[q] * nd);
        *(ushort8v*)&lds_a[r * 136 + lane16 * 8] = o;
    }

    // ---- B fragments (WT hot in L1/L2) ----
    const int lane = t & 63;
    const int w  = t >> 6;
    const int wr = w & 1;
    const int wc = w >> 1;
    const int l15 = lane & 15, quad = lane >> 4;

    short8 bfrag[4][4];
    #pragma unroll
    for (int ks = 0; ks < 4; ++ks)
        #pragma unroll
        for (int tn = 0; tn < 4; ++tn) {
            int n = wc * 64 + tn * 16 + l15;
            bfrag[ks][tn] = *(const short8*)(WT + (size_t)n * 128 + ks * 32 + quad * 8);
        }

    floatx4 acc[4][2];
    #pragma unroll
    for (int tn = 0; tn < 4; ++tn)
        #pragma unroll
        for (int rt = 0; rt < 2; ++rt)
            acc[tn][rt] = (floatx4){0.f, 0.f, 0.f, 0.f};

    __syncthreads();

    // ---- phase 2: MFMA ----
    #pragma unroll
    for (int ks = 0; ks < 4; ++ks) {
        short8 af[2];
        #pragma unroll
        for (int rt = 0; rt < 2; ++rt) {
            int m = wr * 32 + rt * 16 + l15;
            af[rt] = *(const short8*)&lds_a[m * 136 + ks * 32 + quad * 8];
        }
        #pragma unroll
        for (int tn = 0; tn < 4; ++tn)
            #pragma unroll
            for (int rt = 0; rt < 2; ++rt)
                acc[tn][rt] = __builtin_amdgcn_mfma_f32_16x16x32_bf16(
                    af[rt], bfrag[ks][tn], acc[tn][rt], 0, 0, 0);
    }

    // ---- epilogue: bias + silu (+norm_src), repack via LDS, coalesced bf16 stores ----
    __syncthreads();   // everyone done reading lds_a
    #pragma unroll
    for (int tn = 0; tn < 4; ++tn) {
        int col = wc * 64 + tn * 16 + l15;
        float b = bias[col];
        #pragma unroll
        for (int rt = 0; rt < 2; ++rt) {
            #pragma unroll
            for (int r = 0; r < 4; ++r) {
                int row = wr * 32 + rt * 16 + quad * 4 + r;
                float v = silu_f(acc[tn][rt][r] + b);
                if (SCALE_NORM) v *= norm_src[rowbase + row];
                lds_a[row * 136 + col] = f2bf(v);
            }
        }
    }
    __syncthreads();
    #pragma unroll
    for (int j = 0; j < 4; ++j) {
        int e = j * 256 + t;
        int r = e >> 4;
        int c = (e & 15) * 8;
        *(ushort8v*)(out + (size_t)(rowbase + r) * 128 + c) = *(const ushort8v*)&lds_a[r * 136 + c];
    }
}

// ================= standalone bf16 MFMA GEMM (input + output projections) =================
// out always bf16, silu always applied.
template<int KP, bool A_BF16, bool SCALE_NORM>
__launch_bounds__(256)
__global__ void mfma_gemm(const void* __restrict__ in_, const unsigned short* __restrict__ WT,
                          const float* __restrict__ bias, const float* __restrict__ norm_src,
                          unsigned short* __restrict__ out, int nrows) {
    constexpr int KSTEPS = KP / 32;
    __shared__ unsigned short lds_a[64 * 136];
    const int t = threadIdx.x;
    const int rowbase = blockIdx.x * 64;

    if constexpr (A_BF16) {
        const unsigned short* in = (const unsigned short*)in_;
        #pragma unroll
        for (int j = 0; j < 4; ++j) {
            int e = j * 256 + t;
            int r = e >> 4;
            int c = (e & 15) * 8;
            ushort8v u = *(const ushort8v*)(in + (size_t)(rowbase + r) * KP + c);
            *(ushort8v*)&lds_a[r * 136 + c] = u;
        }
    } else {
        // fp32 input [nrows][74], rows 8B-aligned -> float2 loads; pad cols 74..95 with 0
        const float* in = (const float*)in_;
        for (int i = t; i < 64 * 37; i += 256) {
            int r = i / 37, kk = i - r * 37;
            float2 v = *(const float2*)(in + (size_t)(rowbase + r) * IN_F + kk * 2);
            lds_a[r * 136 + kk * 2]     = f2bf(v.x);
            lds_a[r * 136 + kk * 2 + 1] = f2bf(v.y);
        }
        for (int i = t; i < 64 * 22; i += 256) {
            int r = i / 22, kk = 74 + (i - r * 22);
            lds_a[r * 136 + kk] = 0;
        }
    }

    const int lane = t & 63;
    const int w  = t >> 6;
    const int wr = w & 1;
    const int wc = w >> 1;
    const int l15 = lane & 15, quad = lane >> 4;

    short8 bfrag[KSTEPS][4];
    #pragma unroll
    for (int ks = 0; ks < KSTEPS; ++ks)
        #pragma unroll
        for (int tn = 0; tn < 4; ++tn) {
            int n = wc * 64 + tn * 16 + l15;
            bfrag[ks][tn] = *(const short8*)(WT + (size_t)n * KP + ks * 32 + quad * 8);
        }

    floatx4 acc[4][2];
    #pragma unroll
    for (int tn = 0; tn < 4; ++tn)
        #pragma unroll
        for (int rt = 0; rt < 2; ++rt)
            acc[tn][rt] = (floatx4){0.f, 0.f, 0.f, 0.f};

    __syncthreads();

    #pragma unroll
    for (int ks = 0; ks < KSTEPS; ++ks) {
        short8 af[2];
        #pragma unroll
        for (int rt = 0; rt < 2; ++rt) {
            int m = wr * 32 + rt * 16 + l15;
            af[rt] = *(const short8*)&lds_a[m * 136 + ks * 32 + quad * 8];
        }
        #pragma unroll
        for (int tn = 0; tn < 4; ++tn)
            #pragma unroll
            for (int rt = 0; rt < 2; ++rt)
                acc[tn][rt] = __builtin_amdgcn_mfma_f32_16x16x32_bf16(
                    af[rt], bfrag[ks][tn], acc[tn][rt], 0, 0, 0);
    }

    __syncthreads();
    #pragma unroll
    for (int tn = 0; tn < 4; ++tn) {
        int col = wc * 64 + tn * 16 + l15;
        float b = bias[col];
        #pragma unroll
        for (int rt = 0; rt < 2; ++rt) {
            #pragma unroll
            for (int r = 0; r < 4; ++r) {
                int row = wr * 32 + rt * 16 + quad * 4 + r;
                float v = silu_f(acc[tn][rt][r] + b);
                if (SCALE_NORM) v *= norm_src[rowbase + row];
                lds_a[row * 136 + col] = f2bf(v);
            }
        }
    }
    __syncthreads();
    #pragma unroll
    for (int j = 0; j < 4; ++j) {
        int e = j * 256 + t;
        int r = e >> 4;
        int c = (e & 15) * 8;
        *(ushort8v*)(out + (size_t)(rowbase + r) * 128 + c) = *(const ushort8v*)&lds_a[r * 136 + c];
    }
}

// ================= fp32 GEMM (small final matmul) =================
template<int K, bool DO_SILU>
__launch_bounds__(256)
__global__ void gemm_kernel(const float* __restrict__ in, const float* __restrict__ W,
                            const float* __restrict__ bias, float* __restrict__ out, int nrows) {
    __shared__ float wl[64 * HID];
    __shared__ float xl[32 * K];
    int t = threadIdx.x;
    int row0 = blockIdx.x * 32;

    for (int i = t; i < 32 * K; i += 256) {
        int r = i / K, k = i - r * K;
        int gr = row0 + r;
        xl[i] = (gr < nrows) ? in[(size_t)gr * K + k] : 0.0f;
    }

    int col = t & (HID - 1);
    int rg  = t >> 7;
    float acc[16];
    #pragma unroll
    for (int rr = 0; rr < 16; ++rr) acc[rr] = 0.0f;

    for (int c = 0; c < K; c += 64) {
        int kc = (K - c < 64) ? (K - c) : 64;
        __syncthreads();
        for (int i = t; i < kc * HID; i += 256) wl[i] = W[(size_t)c * HID + i];
        __syncthreads();
        for (int kk = 0; kk < kc; ++kk) {
            float w = wl[kk * HID + col];
            int k = c + kk;
            #pragma unroll
            for (int rr = 0; rr < 16; ++rr)
                acc[rr] += xl[(rg * 16 + rr) * K + k] * w;
        }
    }

    float b = bias[col];
    #pragma unroll
    for (int rr = 0; rr < 16; ++rr) {
        int r = row0 + rg * 16 + rr;
        if (r < nrows) {
            float v = acc[rr] + b;
            if (DO_SILU) v = silu_f(v);
            out[(size_t)r * HID + col] = v;
        }
    }
}

// ================= pooling: sorted graph_ids -> segmented sum =================
__device__ __forceinline__ int lower_bound_gid(const int* __restrict__ gid, int val) {
    int lo = 0, hi = N_NODES;
    while (lo < hi) {
        int mid = (lo + hi) >> 1;
        if (gid[mid] < val) lo = mid + 1; else hi = mid;
    }
    return lo;
}

__global__ void pool_kernel(const unsigned short* __restrict__ h, const int* __restrict__ gid,
                            float* __restrict__ pooled) {
    int g = blockIdx.x;
    int t = threadIdx.x;   // 128 threads, one per column
    int beg = lower_bound_gid(gid, g);
    int end = lower_bound_gid(gid, g + 1);
    float s = 0.0f;
    for (int n = beg; n < end; ++n)
        s += bf2f(h[(size_t)n * HID + t]);
    pooled[(size_t)g * HID + t] = s;
}

extern "C" void kernel_launch(void* const* d_in, const int* in_sizes, int n_in,
                              void* d_out, int out_size, void* d_ws, size_t ws_size,
                              hipStream_t stream) {
    const float* x     = (const float*)d_in[0];
    const int*   src   = (const int*)  d_in[1];
    const int*   dst   = (const int*)  d_in[2];
    const int*   gid   = (const int*)  d_in[3];
    const float* w_in  = (const float*)d_in[4];
    const float* b_in  = (const float*)d_in[5];
    const float* gw    = (const float*)d_in[6];
    const float* gb    = (const float*)d_in[7];
    const float* w_out = (const float*)d_in[8];
    const float* b_out = (const float*)d_in[9];
    const float* w_ff  = (const float*)d_in[10];
    const float* b_ff  = (const float*)d_in[11];
    float* out = (float*)d_out;

    char* w = (char*)d_ws;
    size_t off = 0;
    auto alloc = [&](size_t bytes) { void* p = w + off; off += (bytes + 255) & ~(size_t)255; return p; };
    unsigned short* hb0 = (unsigned short*)alloc((size_t)N_NODES * HID * 2);
    unsigned short* hb1 = (unsigned short*)alloc((size_t)N_NODES * HID * 2);
    float* norm_src = (float*)alloc((size_t)N_NODES * 4);
    float* norm_dst = (float*)alloc((size_t)N_NODES * 4);
    int*   row_off  = (int*)  alloc((size_t)(N_NODES + 1) * 4);
    int*   esrc     = (int*)  alloc((size_t)N_EDGES * 4);
    int2*  ebuf     = (int2*) alloc((size_t)N_EDGES * 8);
    int*   sbuf     = (int*)  alloc((size_t)N_EDGES * 4);
    int*   cnt_d    = (int*)  alloc((size_t)NTOT * 4);
    int*   cnt_s    = (int*)  alloc((size_t)NTOT * 4);
    int*   offs_d   = (int*)  alloc((size_t)NTOT * 4);
    int*   offs_s   = (int*)  alloc((size_t)NTOT * 4);
    int*   bsums    = (int*)  alloc(1024 * 4);
    float* pooled   = (float*)alloc((size_t)N_GRAPHS * HID * 4);
    unsigned short* wtin  = (unsigned short*)alloc(128 * 96 * 2);
    unsigned short* wtg   = (unsigned short*)alloc(3 * 128 * 128 * 2);
    unsigned short* wtout = (unsigned short*)alloc(128 * 128 * 2);

    const int NB_SCAN = NTOT / 256;   // 782 exactly

    // ---- CSR build, no global atomics ----
    count_kernel<<<G1, 256, 0, stream>>>(src, dst, cnt_d, cnt_s);
    gscan1<<<NB_SCAN, 256, 0, stream>>>(cnt_d, offs_d, bsums, NTOT);
    gscan2<<<1, 1024, 0, stream>>>(bsums, NB_SCAN);
    gscan3<<<NB_SCAN, 256, 0, stream>>>(offs_d, bsums, NTOT);
    gscan1<<<NB_SCAN, 256, 0, stream>>>(cnt_s, offs_s, bsums, NTOT);
    gscan2<<<1, 1024, 0, stream>>>(bsums, NB_SCAN);
    gscan3<<<NB_SCAN, 256, 0, stream>>>(offs_s, bsums, NTOT);
    scatter_kernel<<<G1, 256, 0, stream>>>(src, dst, offs_d, offs_s, ebuf, sbuf);
    csr_kernel<<<NBUCK, 512, 0, stream>>>(ebuf, offs_d, row_off, esrc, norm_dst);
    degsrc_kernel<<<NBUCK, 512, 0, stream>>>(sbuf, offs_s, norm_src);

    wprep_kernel<<<(128 * 96 + 4 * 128 * 128 + 255) / 256, 256, 0, stream>>>(
        w_in, gw, w_out, wtin, wtg, wtout);

    const int NB_M = N_NODES / 64;   // 3125 exactly

    // h = silu(x @ w_in + b_in) * norm_src   -> bf16
    mfma_gemm<96, false, true><<<NB_M, 256, 0, stream>>>(
        x, wtin, b_in, norm_src, hb0, N_NODES);

    // 3 fused graph convs (gather + GEMM in one kernel)
    fused_conv<true><<<NB_M, 256, 0, stream>>>(
        hb0, esrc, row_off, norm_dst, wtg + 0 * HID * HID, gb + 0 * HID, norm_src, hb1);
    fused_conv<true><<<NB_M, 256, 0, stream>>>(
        hb1, esrc, row_off, norm_dst, wtg + 1 * HID * HID, gb + 1 * HID, norm_src, hb0);
    fused_conv<false><<<NB_M, 256, 0, stream>>>(
        hb0, esrc, row_off, norm_dst, wtg + 2 * HID * HID, gb + 2 * HID, norm_src, hb1);

    // h = silu(h @ w_out + b_out) -> bf16
    mfma_gemm<128, true, false><<<NB_M, 256, 0, stream>>>(
        hb1, wtout, b_out, norm_src, hb0, N_NODES);

    // pooled = segment_sum(h, gid)
    pool_kernel<<<N_GRAPHS, HID, 0, stream>>>(hb0, gid, pooled);

    // out = pooled @ w_ff + b_ff (fp32)
    gemm_kernel<HID, false><<<(N_GRAPHS + 31) / 32, 256, 0, stream>>>(pooled, w_ff, b_ff, out, N_GRAPHS);
}

// Round 8
// 618.167 us; speedup vs baseline: 3.5091x; 1.1340x over previous
//
#include <hip/hip_runtime.h>
#include <math.h>

#define N_NODES  200000
#define N_EDGES  1600000
#define N_GRAPHS 10000
#define IN_F     74
#define HID      128
#define DEPTH    3

#define NBUCK 391          // ceil(N_NODES / 512): bucket = id >> 9
#define G1    512          // blocks in count/scatter pass
#define CHUNK 3125         // N_EDGES / G1 (exact)
#define NTOT  (NBUCK * G1) // 200192 scan elements

typedef __attribute__((ext_vector_type(8))) short short8;
typedef __attribute__((ext_vector_type(8))) unsigned short ushort8v;
typedef __attribute__((ext_vector_type(4))) float floatx4;

__device__ __forceinline__ float silu_f(float x) {
    return x / (1.0f + __expf(-x));
}

__device__ __forceinline__ unsigned short f2bf(float f) {
    union { float f; unsigned int u; } v; v.f = f;
    unsigned int r = (v.u + 0x7fff + ((v.u >> 16) & 1)) >> 16;   // RNE
    return (unsigned short)r;
}

__device__ __forceinline__ float bf2f(unsigned short u) {
    union { unsigned int u; float f; } v; v.u = ((unsigned int)u) << 16;
    return v.f;
}

// ================= atomic-free CSR build (radix partition by id>>9) =================

__global__ void count_kernel(const int* __restrict__ src, const int* __restrict__ dst,
                             int* __restrict__ cnt_d, int* __restrict__ cnt_s) {
    __shared__ int hd[NBUCK], hs[NBUCK];
    int t = threadIdx.x, b = blockIdx.x;
    for (int i = t; i < NBUCK; i += 256) { hd[i] = 0; hs[i] = 0; }
    __syncthreads();
    int e0 = b * CHUNK;
    for (int i = t; i < CHUNK; i += 256) {
        int e = e0 + i;
        atomicAdd(&hd[dst[e] >> 9], 1);
        atomicAdd(&hs[src[e] >> 9], 1);
    }
    __syncthreads();
    for (int i = t; i < NBUCK; i += 256) {
        cnt_d[i * G1 + b] = hd[i];
        cnt_s[i * G1 + b] = hs[i];
    }
}

__global__ void gscan1(const int* __restrict__ in, int* __restrict__ out,
                       int* __restrict__ bsums, int n) {
    __shared__ int a[256], b2[256];
    int t = threadIdx.x;
    int i = blockIdx.x * 256 + t;
    a[t] = (i < n) ? in[i] : 0;
    __syncthreads();
    int* s = a; int* d = b2;
    #pragma unroll
    for (int off = 1; off < 256; off <<= 1) {
        int v = s[t];
        if (t >= off) v += s[t - off];
        d[t] = v;
        __syncthreads();
        int* tmp = s; s = d; d = tmp;
    }
    if (i < n) out[i] = (t ? s[t - 1] : 0);
    if (t == 255) bsums[blockIdx.x] = s[255];
}

__global__ void gscan2(int* __restrict__ bsums, int nb) {
    __shared__ int a[1024], b[1024];
    int t = threadIdx.x;
    a[t] = (t < nb) ? bsums[t] : 0;
    __syncthreads();
    int* s = a; int* d = b;
    for (int off = 1; off < 1024; off <<= 1) {
        int v = s[t];
        if (t >= off) v += s[t - off];
        d[t] = v;
        __syncthreads();
        int* tmp = s; s = d; d = tmp;
    }
    if (t < nb) bsums[t] = s[t];
}

__global__ void gscan3(int* __restrict__ out, const int* __restrict__ bsums, int n) {
    int i = blockIdx.x * 256 + threadIdx.x;
    if (i < n && blockIdx.x > 0) out[i] += bsums[blockIdx.x - 1];
}

__global__ void scatter_kernel(const int* __restrict__ src, const int* __restrict__ dst,
                               const int* __restrict__ offs_d, const int* __restrict__ offs_s,
                               int2* __restrict__ ebuf, int* __restrict__ sbuf) {
    __shared__ int cd[NBUCK], cs[NBUCK];
    int t = threadIdx.x, b = blockIdx.x;
    for (int i = t; i < NBUCK; i += 256) {
        cd[i] = offs_d[i * G1 + b];
        cs[i] = offs_s[i * G1 + b];
    }
    __syncthreads();
    int e0 = b * CHUNK;
    for (int i = t; i < CHUNK; i += 256) {
        int e = e0 + i;
        int d = dst[e], s = src[e];
        int pd = atomicAdd(&cd[d >> 9], 1);
        int2 p; p.x = d; p.y = s;
        ebuf[pd] = p;
        int ps = atomicAdd(&cs[s >> 9], 1);
        sbuf[ps] = s;
    }
}

__global__ __launch_bounds__(512)
void csr_kernel(const int2* __restrict__ ebuf, const int* __restrict__ offs_d,
                int* __restrict__ row_off, int* __restrict__ esrc,
                float* __restrict__ norm_dst) {
    __shared__ int deg[512];
    __shared__ int sa[512], sb[512];
    int k = blockIdx.x, t = threadIdx.x;
    int base = k << 9;
    int estart = offs_d[k * G1];
    int eend = (k + 1 < NBUCK) ? offs_d[(k + 1) * G1] : N_EDGES;
    deg[t] = 0;
    __syncthreads();
    for (int e = estart + t; e < eend; e += 512)
        atomicAdd(&deg[ebuf[e].x - base], 1);
    __syncthreads();
    sa[t] = deg[t];
    __syncthreads();
    int* ps = sa; int* pd = sb;
    #pragma unroll
    for (int off = 1; off < 512; off <<= 1) {
        int v = ps[t];
        if (t >= off) v += ps[t - off];
        pd[t] = v;
        __syncthreads();
        int* tmp = ps; ps = pd; pd = tmp;
    }
    int excl = t ? ps[t - 1] : 0;
    int n = base + t;
    if (n <= N_NODES) row_off[n] = estart + excl;
    if (n < N_NODES)  norm_dst[n] = rsqrtf(fmaxf((float)deg[t], 1.0f));
    __syncthreads();
    pd[t] = estart + excl;
    __syncthreads();
    for (int e = estart + t; e < eend; e += 512) {
        int2 ed = ebuf[e];
        int pos = atomicAdd(&pd[ed.x - base], 1);
        esrc[pos] = ed.y;
    }
}

__global__ __launch_bounds__(512)
void degsrc_kernel(const int* __restrict__ sbuf, const int* __restrict__ offs_s,
                   float* __restrict__ norm_src) {
    __shared__ int deg[512];
    int k = blockIdx.x, t = threadIdx.x;
    int base = k << 9;
    int estart = offs_s[k * G1];
    int eend = (k + 1 < NBUCK) ? offs_s[(k + 1) * G1] : N_EDGES;
    deg[t] = 0;
    __syncthreads();
    for (int e = estart + t; e < eend; e += 512)
        atomicAdd(&deg[sbuf[e] - base], 1);
    __syncthreads();
    int n = base + t;
    if (n < N_NODES) norm_src[n] = rsqrtf(fmaxf((float)deg[t], 1.0f));
}

// ================= weight prep =================
__global__ void wprep_kernel(const float* __restrict__ w_in, const float* __restrict__ gw,
                             const float* __restrict__ w_out,
                             unsigned short* __restrict__ wtin,   // [128][96]
                             unsigned short* __restrict__ wtg,    // [3][128][128]
                             unsigned short* __restrict__ wtout)  // [128][128]
{
    int i = blockIdx.x * 256 + threadIdx.x;
    if (i < 128 * 96) {
        int n = i / 96, k = i - n * 96;
        wtin[i] = (k < IN_F) ? f2bf(w_in[k * 128 + n]) : (unsigned short)0;
    } else if (i < 128 * 96 + 3 * 128 * 128) {
        int j = i - 128 * 96;
        int layer = j / 16384, r = j - layer * 16384;
        int n = r >> 7, k = r & 127;
        wtg[j] = f2bf(gw[((size_t)layer * 128 + k) * 128 + n]);
    } else if (i < 128 * 96 + 3 * 128 * 128 + 128 * 128) {
        int j = i - (128 * 96 + 3 * 128 * 128);
        int n = j >> 7, k = j & 127;
        wtout[j] = f2bf(w_out[k * 128 + n]);
    }
}

// ================= fused conv: gather(SpMM) -> MFMA -> silu [-> MFMA2 -> silu] =================
// Block: 256 threads, 64 dst nodes. h is bf16 pre-scaled by norm_src.
// SECOND: run a second GEMM (w_out) on the conv output tile before storing.
template<bool SCALE_NORM, bool SECOND>
__launch_bounds__(256)
__global__ void fused_conv(const unsigned short* __restrict__ h,
                           const int* __restrict__ esrc, const int* __restrict__ row_off,
                           const float* __restrict__ norm_dst,
                           const unsigned short* __restrict__ WT,   // [128][128]
                           const float* __restrict__ bias, const float* __restrict__ norm_src,
                           const unsigned short* __restrict__ WT2,  // [128][128] (SECOND)
                           const float* __restrict__ bias2,
                           unsigned short* __restrict__ out) {
    __shared__ unsigned short lds_a[64 * 136];    // A tile / C repack (stride 136 >= 128: no aliasing)
    __shared__ unsigned short lds_b[128 * 136];   // B tile
    const int t = threadIdx.x;
    const int rowbase = blockIdx.x * 64;
    const int grp = t >> 4;          // 0..15
    const int lane16 = t & 15;

    // ---- issue B1 -> LDS first (overlaps with gather) ----
    #pragma unroll
    for (int j = 0; j < 8; ++j) {
        int slot = j * 256 + t;
        int n = slot >> 4, k = (slot & 15) * 8;
        *(ushort8v*)&lds_b[n * 136 + k] = *(const ushort8v*)(WT + n * 128 + k);
    }

    // ---- phase 1: gather agg rows (bf16) into LDS ----
    #pragma unroll
    for (int g = 0; g < 4; ++g) {
        int r = g * 16 + grp;
        int node = rowbase + r;
        int beg = row_off[node], end = row_off[node + 1];
        float acc[8];
        #pragma unroll
        for (int q = 0; q < 8; ++q) acc[q] = 0.0f;
        int j = beg;
        for (; j + 7 < end; j += 8) {
            ushort8v v[8];
            #pragma unroll
            for (int u = 0; u < 8; ++u)
                v[u] = *(const ushort8v*)(h + (size_t)esrc[j + u] * HID + lane16 * 8);
            #pragma unroll
            for (int q = 0; q < 8; ++q)
                acc[q] += ((bf2f(v[0][q]) + bf2f(v[1][q])) + (bf2f(v[2][q]) + bf2f(v[3][q])))
                        + ((bf2f(v[4][q]) + bf2f(v[5][q])) + (bf2f(v[6][q]) + bf2f(v[7][q])));
        }
        for (; j + 3 < end; j += 4) {
            ushort8v v[4];
            #pragma unroll
            for (int u = 0; u < 4; ++u)
                v[u] = *(const ushort8v*)(h + (size_t)esrc[j + u] * HID + lane16 * 8);
            #pragma unroll
            for (int q = 0; q < 8; ++q)
                acc[q] += (bf2f(v[0][q]) + bf2f(v[1][q])) + (bf2f(v[2][q]) + bf2f(v[3][q]));
        }
        for (; j < end; ++j) {
            ushort8v v0 = *(const ushort8v*)(h + (size_t)esrc[j] * HID + lane16 * 8);
            #pragma unroll
            for (int q = 0; q < 8; ++q)
                acc[q] += bf2f(v0[q]);
        }
        float nd = norm_dst[node];
        ushort8v o;
        #pragma unroll
        for (int q = 0; q < 8; ++q) o[q] = f2bf(acc[q] * nd);
        *(ushort8v*)&lds_a[r * 136 + lane16 * 8] = o;
    }

    const int lane = t & 63;
    const int w  = t >> 6;
    const int wr = w & 1;
    const int wc = w >> 1;
    const int l15 = lane & 15, quad = lane >> 4;

    floatx4 acc[4][2];
    #pragma unroll
    for (int tn = 0; tn < 4; ++tn)
        #pragma unroll
        for (int rt = 0; rt < 2; ++rt)
            acc[tn][rt] = (floatx4){0.f, 0.f, 0.f, 0.f};

    __syncthreads();

    // ---- K-loop 1: A,B from LDS ----
    #pragma unroll
    for (int ks = 0; ks < 4; ++ks) {
        short8 bk[4];
        #pragma unroll
        for (int tn = 0; tn < 4; ++tn)
            bk[tn] = *(const short8*)&lds_b[(wc * 64 + tn * 16 + l15) * 136 + ks * 32 + quad * 8];
        short8 af[2];
        #pragma unroll
        for (int rt = 0; rt < 2; ++rt)
            af[rt] = *(const short8*)&lds_a[(wr * 32 + rt * 16 + l15) * 136 + ks * 32 + quad * 8];
        #pragma unroll
        for (int tn = 0; tn < 4; ++tn)
            #pragma unroll
            for (int rt = 0; rt < 2; ++rt)
                acc[tn][rt] = __builtin_amdgcn_mfma_f32_16x16x32_bf16(
                    af[rt], bk[tn], acc[tn][rt], 0, 0, 0);
    }

    __syncthreads();

    // ---- epilogue 1: bias + silu (+norm_src) -> lds_a ----
    #pragma unroll
    for (int tn = 0; tn < 4; ++tn) {
        int col = wc * 64 + tn * 16 + l15;
        float b = bias[col];
        #pragma unroll
        for (int rt = 0; rt < 2; ++rt) {
            #pragma unroll
            for (int r = 0; r < 4; ++r) {
                int row = wr * 32 + rt * 16 + quad * 4 + r;
                float v = silu_f(acc[tn][rt][r] + b);
                if (SCALE_NORM) v *= norm_src[rowbase + row];
                lds_a[row * 136 + col] = f2bf(v);
            }
        }
    }

    if constexpr (SECOND) {
        // ---- load B2 -> lds_b ----
        #pragma unroll
        for (int j = 0; j < 8; ++j) {
            int slot = j * 256 + t;
            int n = slot >> 4, k = (slot & 15) * 8;
            *(ushort8v*)&lds_b[n * 136 + k] = *(const ushort8v*)(WT2 + n * 128 + k);
        }
        #pragma unroll
        for (int tn = 0; tn < 4; ++tn)
            #pragma unroll
            for (int rt = 0; rt < 2; ++rt)
                acc[tn][rt] = (floatx4){0.f, 0.f, 0.f, 0.f};
        __syncthreads();

        // ---- K-loop 2 ----
        #pragma unroll
        for (int ks = 0; ks < 4; ++ks) {
            short8 bk[4];
            #pragma unroll
            for (int tn = 0; tn < 4; ++tn)
                bk[tn] = *(const short8*)&lds_b[(wc * 64 + tn * 16 + l15) * 136 + ks * 32 + quad * 8];
            short8 af[2];
            #pragma unroll
            for (int rt = 0; rt < 2; ++rt)
                af[rt] = *(const short8*)&lds_a[(wr * 32 + rt * 16 + l15) * 136 + ks * 32 + quad * 8];
            #pragma unroll
            for (int tn = 0; tn < 4; ++tn)
                #pragma unroll
                for (int rt = 0; rt < 2; ++rt)
                    acc[tn][rt] = __builtin_amdgcn_mfma_f32_16x16x32_bf16(
                        af[rt], bk[tn], acc[tn][rt], 0, 0, 0);
        }

        __syncthreads();
        // ---- epilogue 2: bias2 + silu -> lds_a ----
        #pragma unroll
        for (int tn = 0; tn < 4; ++tn) {
            int col = wc * 64 + tn * 16 + l15;
            float b = bias2[col];
            #pragma unroll
            for (int rt = 0; rt < 2; ++rt) {
                #pragma unroll
                for (int r = 0; r < 4; ++r) {
                    int row = wr * 32 + rt * 16 + quad * 4 + r;
                    lds_a[row * 136 + col] = f2bf(silu_f(acc[tn][rt][r] + b));
                }
            }
        }
    }

    __syncthreads();
    // ---- coalesced bf16 store ----
    #pragma unroll
    for (int j = 0; j < 4; ++j) {
        int e = j * 256 + t;
        int r = e >> 4;
        int c = (e & 15) * 8;
        *(ushort8v*)(out + (size_t)(rowbase + r) * 128 + c) = *(const ushort8v*)&lds_a[r * 136 + c];
    }
}

// ================= input projection: fp32 x [N][74] @ wtin -> silu * norm_src -> bf16 =================
__launch_bounds__(256)
__global__ void inproj_gemm(const float* __restrict__ in, const unsigned short* __restrict__ WT,
                            const float* __restrict__ bias, const float* __restrict__ norm_src,
                            unsigned short* __restrict__ out) {
    // ASTR=136: lds_a doubles as 128-col C repack buffer (stride must be >=128 to avoid
    // row aliasing -- the Round-6 bug was ASTR=104 here). BSTR=104 for the 96-col B tile.
    constexpr int KP = 96, ASTR = 136, BSTR = 104;
    __shared__ unsigned short lds_a[64 * ASTR];
    __shared__ unsigned short lds_b[128 * BSTR];
    const int t = threadIdx.x;
    const int rowbase = blockIdx.x * 64;

    // B -> LDS (128 x 96): 1536 ushort8 slots, 6 per thread
    #pragma unroll
    for (int j = 0; j < 6; ++j) {
        int slot = j * 256 + t;
        int n = slot / 12, k = (slot - n * 12) * 8;
        *(ushort8v*)&lds_b[n * BSTR + k] = *(const ushort8v*)(WT + n * KP + k);
    }

    // A: fp32 rows of 74, float2 loads; pad 74..95 with 0
    for (int i = t; i < 64 * 37; i += 256) {
        int r = i / 37, kk = (i - r * 37) * 2;
        float2 v = *(const float2*)(in + (size_t)(rowbase + r) * IN_F + kk);
        lds_a[r * ASTR + kk]     = f2bf(v.x);
        lds_a[r * ASTR + kk + 1] = f2bf(v.y);
    }
    for (int i = t; i < 64 * 22; i += 256) {
        int r = i / 22, kk = 74 + (i - r * 22);
        lds_a[r * ASTR + kk] = 0;
    }

    const int lane = t & 63;
    const int w  = t >> 6;
    const int wr = w & 1;
    const int wc = w >> 1;
    const int l15 = lane & 15, quad = lane >> 4;

    floatx4 acc[4][2];
    #pragma unroll
    for (int tn = 0; tn < 4; ++tn)
        #pragma unroll
        for (int rt = 0; rt < 2; ++rt)
            acc[tn][rt] = (floatx4){0.f, 0.f, 0.f, 0.f};

    __syncthreads();

    #pragma unroll
    for (int ks = 0; ks < 3; ++ks) {
        short8 bk[4];
        #pragma unroll
        for (int tn = 0; tn < 4; ++tn)
            bk[tn] = *(const short8*)&lds_b[(wc * 64 + tn * 16 + l15) * BSTR + ks * 32 + quad * 8];
        short8 af[2];
        #pragma unroll
        for (int rt = 0; rt < 2; ++rt)
            af[rt] = *(const short8*)&lds_a[(wr * 32 + rt * 16 + l15) * ASTR + ks * 32 + quad * 8];
        #pragma unroll
        for (int tn = 0; tn < 4; ++tn)
            #pragma unroll
            for (int rt = 0; rt < 2; ++rt)
                acc[tn][rt] = __builtin_amdgcn_mfma_f32_16x16x32_bf16(
                    af[rt], bk[tn], acc[tn][rt], 0, 0, 0);
    }

    __syncthreads();
    #pragma unroll
    for (int tn = 0; tn < 4; ++tn) {
        int col = wc * 64 + tn * 16 + l15;
        float b = bias[col];
        #pragma unroll
        for (int rt = 0; rt < 2; ++rt) {
            #pragma unroll
            for (int r = 0; r < 4; ++r) {
                int row = wr * 32 + rt * 16 + quad * 4 + r;
                float v = silu_f(acc[tn][rt][r] + b) * norm_src[rowbase + row];
                lds_a[row * ASTR + col] = f2bf(v);
            }
        }
    }
    __syncthreads();
    #pragma unroll
    for (int j = 0; j < 4; ++j) {
        int e = j * 256 + t;
        int r = e >> 4;
        int c = (e & 15) * 8;
        *(ushort8v*)(out + (size_t)(rowbase + r) * 128 + c) = *(const ushort8v*)&lds_a[r * ASTR + c];
    }
}

// ================= fp32 GEMM (small final matmul) =================
template<int K, bool DO_SILU>
__launch_bounds__(256)
__global__ void gemm_kernel(const float* __restrict__ in, const float* __restrict__ W,
                            const float* __restrict__ bias, float* __restrict__ out, int nrows) {
    __shared__ float wl[64 * HID];
    __shared__ float xl[32 * K];
    int t = threadIdx.x;
    int row0 = blockIdx.x * 32;

    for (int i = t; i < 32 * K; i += 256) {
        int r = i / K, k = i - r * K;
        int gr = row0 + r;
        xl[i] = (gr < nrows) ? in[(size_t)gr * K + k] : 0.0f;
    }

    int col = t & (HID - 1);
    int rg  = t >> 7;
    float acc[16];
    #pragma unroll
    for (int rr = 0; rr < 16; ++rr) acc[rr] = 0.0f;

    for (int c = 0; c < K; c += 64) {
        int kc = (K - c < 64) ? (K - c) : 64;
        __syncthreads();
        for (int i = t; i < kc * HID; i += 256) wl[i] = W[(size_t)c * HID + i];
        __syncthreads();
        for (int kk = 0; kk < kc; ++kk) {
            float w = wl[kk * HID + col];
            int k = c + kk;
            #pragma unroll
            for (int rr = 0; rr < 16; ++rr)
                acc[rr] += xl[(rg * 16 + rr) * K + k] * w;
        }
    }

    float b = bias[col];
    #pragma unroll
    for (int rr = 0; rr < 16; ++rr) {
        int r = row0 + rg * 16 + rr;
        if (r < nrows) {
            float v = acc[rr] + b;
            if (DO_SILU) v = silu_f(v);
            out[(size_t)r * HID + col] = v;
        }
    }
}

// ================= pooling: sorted graph_ids -> segmented sum =================
__device__ __forceinline__ int lower_bound_gid(const int* __restrict__ gid, int val) {
    int lo = 0, hi = N_NODES;
    while (lo < hi) {
        int mid = (lo + hi) >> 1;
        if (gid[mid] < val) lo = mid + 1; else hi = mid;
    }
    return lo;
}

// 256 threads = 4 graphs x 64 lanes; each lane sums 2 columns via uint loads
__global__ void pool_kernel(const unsigned short* __restrict__ h, const int* __restrict__ gid,
                            float* __restrict__ pooled) {
    int g = blockIdx.x * 4 + (threadIdx.x >> 6);
    int lane = threadIdx.x & 63;
    int beg = lower_bound_gid(gid, g);
    int end = lower_bound_gid(gid, g + 1);
    float s0 = 0.0f, s1 = 0.0f;
    const unsigned int* hp = (const unsigned int*)h;
    for (int n = beg; n < end; ++n) {
        unsigned int u = hp[(size_t)n * 64 + lane];
        s0 += bf2f((unsigned short)(u & 0xffff));
        s1 += bf2f((unsigned short)(u >> 16));
    }
    float2 o; o.x = s0; o.y = s1;
    *(float2*)(pooled + (size_t)g * HID + lane * 2) = o;
}

extern "C" void kernel_launch(void* const* d_in, const int* in_sizes, int n_in,
                              void* d_out, int out_size, void* d_ws, size_t ws_size,
                              hipStream_t stream) {
    const float* x     = (const float*)d_in[0];
    const int*   src   = (const int*)  d_in[1];
    const int*   dst   = (const int*)  d_in[2];
    const int*   gid   = (const int*)  d_in[3];
    const float* w_in  = (const float*)d_in[4];
    const float* b_in  = (const float*)d_in[5];
    const float* gw    = (const float*)d_in[6];
    const float* gb    = (const float*)d_in[7];
    const float* w_out = (const float*)d_in[8];
    const float* b_out = (const float*)d_in[9];
    const float* w_ff  = (const float*)d_in[10];
    const float* b_ff  = (const float*)d_in[11];
    float* out = (float*)d_out;

    char* w = (char*)d_ws;
    size_t off = 0;
    auto alloc = [&](size_t bytes) { void* p = w + off; off += (bytes + 255) & ~(size_t)255; return p; };
    unsigned short* hb0 = (unsigned short*)alloc((size_t)N_NODES * HID * 2);
    unsigned short* hb1 = (unsigned short*)alloc((size_t)N_NODES * HID * 2);
    float* norm_src = (float*)alloc((size_t)N_NODES * 4);
    float* norm_dst = (float*)alloc((size_t)N_NODES * 4);
    int*   row_off  = (int*)  alloc((size_t)(N_NODES + 1) * 4);
    int*   esrc     = (int*)  alloc((size_t)N_EDGES * 4);
    int2*  ebuf     = (int2*) alloc((size_t)N_EDGES * 8);
    int*   sbuf     = (int*)  alloc((size_t)N_EDGES * 4);
    int*   cnt_d    = (int*)  alloc((size_t)NTOT * 4);
    int*   cnt_s    = (int*)  alloc((size_t)NTOT * 4);
    int*   offs_d   = (int*)  alloc((size_t)NTOT * 4);
    int*   offs_s   = (int*)  alloc((size_t)NTOT * 4);
    int*   bsums    = (int*)  alloc(1024 * 4);
    float* pooled   = (float*)alloc((size_t)N_GRAPHS * HID * 4);
    unsigned short* wtin  = (unsigned short*)alloc(128 * 96 * 2);
    unsigned short* wtg   = (unsigned short*)alloc(3 * 128 * 128 * 2);
    unsigned short* wtout = (unsigned short*)alloc(128 * 128 * 2);

    const int NB_SCAN = NTOT / 256;   // 782 exactly

    // ---- CSR build, no global atomics ----
    count_kernel<<<G1, 256, 0, stream>>>(src, dst, cnt_d, cnt_s);
    gscan1<<<NB_SCAN, 256, 0, stream>>>(cnt_d, offs_d, bsums, NTOT);
    gscan2<<<1, 1024, 0, stream>>>(bsums, NB_SCAN);
    gscan3<<<NB_SCAN, 256, 0, stream>>>(offs_d, bsums, NTOT);
    gscan1<<<NB_SCAN, 256, 0, stream>>>(cnt_s, offs_s, bsums, NTOT);
    gscan2<<<1, 1024, 0, stream>>>(bsums, NB_SCAN);
    gscan3<<<NB_SCAN, 256, 0, stream>>>(offs_s, bsums, NTOT);
    scatter_kernel<<<G1, 256, 0, stream>>>(src, dst, offs_d, offs_s, ebuf, sbuf);
    csr_kernel<<<NBUCK, 512, 0, stream>>>(ebuf, offs_d, row_off, esrc, norm_dst);
    degsrc_kernel<<<NBUCK, 512, 0, stream>>>(sbuf, offs_s, norm_src);

    wprep_kernel<<<(128 * 96 + 4 * 128 * 128 + 255) / 256, 256, 0, stream>>>(
        w_in, gw, w_out, wtin, wtg, wtout);

    const int NB_M = N_NODES / 64;   // 3125 exactly

    // h = silu(x @ w_in + b_in) * norm_src   -> bf16
    inproj_gemm<<<NB_M, 256, 0, stream>>>(x, wtin, b_in, norm_src, hb0);

    // conv1, conv2 (fused gather+GEMM), conv3+out-proj (double GEMM)
    fused_conv<true,  false><<<NB_M, 256, 0, stream>>>(
        hb0, esrc, row_off, norm_dst, wtg + 0 * HID * HID, gb + 0 * HID, norm_src,
        (const unsigned short*)nullptr, (const float*)nullptr, hb1);
    fused_conv<true,  false><<<NB_M, 256, 0, stream>>>(
        hb1, esrc, row_off, norm_dst, wtg + 1 * HID * HID, gb + 1 * HID, norm_src,
        (const unsigned short*)nullptr, (const float*)nullptr, hb0);
    fused_conv<false, true><<<NB_M, 256, 0, stream>>>(
        hb0, esrc, row_off, norm_dst, wtg + 2 * HID * HID, gb + 2 * HID, norm_src,
        wtout, b_out, hb1);

    // pooled = segment_sum(h, gid)
    pool_kernel<<<N_GRAPHS / 4, 256, 0, stream>>>(hb1, gid, pooled);

    // out = pooled @ w_ff + b_ff (fp32)
    gemm_kernel<HID, false><<<(N_GRAPHS + 31) / 32, 256, 0, stream>>>(pooled, w_ff, b_ff, out, N_GRAPHS);
}